// Round 4
// baseline (1023.105 us; speedup 1.0000x reference)
//
#include <hip/hip_runtime.h>

// ---------- problem constants ----------
#define BATCH 2
#define SEQ   2048
#define HID   2048
#define NH    16
#define NKV   8
#define HD    128
#define M_ROWS (BATCH * SEQ)          // 4096
#define QKV_N  4096                   // 2048 q | 1024 k | 1024 v

typedef __attribute__((ext_vector_type(8))) __bf16 bf16x8;
typedef __attribute__((ext_vector_type(4))) float  f32x4;

static __device__ __forceinline__ f32x4 mfma16(bf16x8 a, bf16x8 b, f32x4 c) {
    return __builtin_amdgcn_mfma_f32_16x16x32_bf16(a, b, c, 0, 0, 0);
}
static __device__ __forceinline__ float sigma_f(float x) {
    return x > 0.f ? x + 1.f : __expf(x);   // elu(x)+1
}
// async global->LDS, 16B per lane; lds base must be wave-uniform
static __device__ __forceinline__ void gload16(const __bf16* g, __bf16* l) {
    __builtin_amdgcn_global_load_lds(
        (const __attribute__((address_space(1))) void*)g,
        (__attribute__((address_space(3))) void*)l, 16, 0, 0);
}

// ---------- workspace layout (bytes) ----------
#define OFF_QKV  0ull                              // float [4096][4096]   64 MB
#define OFF_SQ   67108864ull                       // bf16  (b,h,S,128)    16 MB  (pre-GEMM: hb)
#define OFF_QR   83886080ull                       // bf16  (b,h,S,128)    16 MB  (pre-GEMM: qkvT)
#define OFF_KR   100663296ull                      // bf16  (b,kvh,S,128)   8 MB
#define OFF_VT   109051904ull                      // bf16  (b,kvh,128,S)   8 MB
#define OFF_ND   117440512ull                      // float (b,h,S)       256 KB
#define OFF_CB   117702656ull                      // bf16  [4096][2048]   16 MB
#define OFF_PART 134479872ull                      // float 8*(b,kvh,128,128) 8 MB (late: woT 8 MB)
#define OFF_BND  142868480ull                      // float (b,h,S)       256 KB  (q row-norm^2)
#define OFF_MAXK 143130624ull                      // uint  (b,kvh)        64 B   (max k-norm^2 bits)
#define NSPLIT 8

// =====================================================================
// K0a: fp32 -> bf16 bulk convert (8 elems/thread)
// =====================================================================
__global__ void f2b_k(const float* __restrict__ src, __bf16* __restrict__ dst)
{
    const size_t i = ((size_t)blockIdx.x * 256 + threadIdx.x) * 8;
    const float4 v0 = *reinterpret_cast<const float4*>(src + i);
    const float4 v1 = *reinterpret_cast<const float4*>(src + i + 4);
    bf16x8 t;
    t[0]=(__bf16)v0.x; t[1]=(__bf16)v0.y; t[2]=(__bf16)v0.z; t[3]=(__bf16)v0.w;
    t[4]=(__bf16)v1.x; t[5]=(__bf16)v1.y; t[6]=(__bf16)v1.z; t[7]=(__bf16)v1.w;
    *reinterpret_cast<bf16x8*>(dst + i) = t;
}

// =====================================================================
// K0b: W fp32 [K][N] -> Bt bf16 [N][K]  (64x64 LDS tile transpose)
// =====================================================================
__global__ __launch_bounds__(256) void tr_k(const float* __restrict__ W,
                                            __bf16* __restrict__ Bt, int K, int N)
{
    __shared__ __bf16 T[64][72];
    const int k0 = blockIdx.x * 64, n0 = blockIdx.y * 64;
    const int t = threadIdx.x;
    #pragma unroll
    for (int i = 0; i < 4; ++i) {
        const int idx = t + i * 256;           // 0..1023
        const int r = idx >> 4, c4 = (idx & 15) * 4;
        const float4 v = *reinterpret_cast<const float4*>(&W[(size_t)(k0 + r) * N + n0 + c4]);
        T[c4 + 0][r] = (__bf16)v.x; T[c4 + 1][r] = (__bf16)v.y;
        T[c4 + 2][r] = (__bf16)v.z; T[c4 + 3][r] = (__bf16)v.w;
    }
    __syncthreads();
    #pragma unroll
    for (int i = 0; i < 2; ++i) {
        const int idx = t + i * 256;           // 0..511
        const int rr = idx >> 3, cc = (idx & 7) * 8;
        *reinterpret_cast<bf16x8*>(&Bt[(size_t)(n0 + rr) * K + k0 + cc]) =
            *reinterpret_cast<bf16x8*>(&T[rr][cc]);
    }
}

// =====================================================================
// K1 / K8: m97-style GEMM. C[M][N] = A[M][K] @ Bt[N][K]^T, fp32 out.
// 128x128 tile, BK=32, global_load_lds width-16 staging.
// =====================================================================
__global__ __launch_bounds__(256) void gemm_bt(const __bf16* __restrict__ A,
                                               const __bf16* __restrict__ Bt,
                                               float* __restrict__ C,
                                               int N, int K)
{
    __shared__ __align__(16) __bf16 As[128 * 32];
    __shared__ __align__(16) __bf16 Bs[128 * 32];

    const int tid = threadIdx.x, wave = tid >> 6, lane = tid & 63;
    const int l15 = lane & 15, l4 = lane >> 4;
    const int m0 = blockIdx.x * 128, n0 = blockIdx.y * 128;
    const int wm = (wave & 1) * 64, wn = (wave >> 1) * 64;

    f32x4 acc[4][4] = {};

    const int srow = wave * 32 + (lane >> 2);
    const int scol = (lane & 3) * 8;
    const __bf16* Ab = A  + (size_t)(m0 + srow) * K + scol;
    const __bf16* Bb = Bt + (size_t)(n0 + srow) * K + scol;
    __bf16* AsB0 = &As[(wave * 32) * 32];
    __bf16* AsB1 = &As[(wave * 32 + 16) * 32];
    __bf16* BsB0 = &Bs[(wave * 32) * 32];
    __bf16* BsB1 = &Bs[(wave * 32 + 16) * 32];

    for (int kb = 0; kb < K; kb += 32) {
        gload16(Ab + kb,            AsB0);
        gload16(Ab + 16 * K + kb,   AsB1);
        gload16(Bb + kb,            BsB0);
        gload16(Bb + 16 * K + kb,   BsB1);
        __syncthreads();

        bf16x8 af[4], bfr[4];
        #pragma unroll
        for (int mt = 0; mt < 4; ++mt)
            af[mt] = *reinterpret_cast<bf16x8*>(&As[(wm + mt * 16 + l15) * 32 + l4 * 8]);
        #pragma unroll
        for (int nt = 0; nt < 4; ++nt)
            bfr[nt] = *reinterpret_cast<bf16x8*>(&Bs[(wn + nt * 16 + l15) * 32 + l4 * 8]);
        #pragma unroll
        for (int mt = 0; mt < 4; ++mt)
            #pragma unroll
            for (int nt = 0; nt < 4; ++nt)
                acc[mt][nt] = mfma16(af[mt], bfr[nt], acc[mt][nt]);
        __syncthreads();
    }

    #pragma unroll
    for (int mt = 0; mt < 4; ++mt)
        #pragma unroll
        for (int nt = 0; nt < 4; ++nt)
            #pragma unroll
            for (int r = 0; r < 4; ++r) {
                const int row = m0 + wm + mt * 16 + l4 * 4 + r;
                const int col = n0 + wn + nt * 16 + l15;
                C[(size_t)row * N + col] = acc[mt][nt][r];
            }
}

// =====================================================================
// K2: sigma_q, norm dots, RoPE(q,k), V^T, q/k norms — one block per (b,h,s)
// qr is pre-scaled by 1/sqrt(HD). bnd = ||q_rot||^2 ; maxk = atomicMax ||k_rot||^2
// =====================================================================
__global__ void prep_k(const float* __restrict__ qkv, const float* __restrict__ norm_in,
                       const int* __restrict__ pos_ids,
                       __bf16* __restrict__ sq, __bf16* __restrict__ qr,
                       __bf16* __restrict__ kr, __bf16* __restrict__ vt,
                       float* __restrict__ nd, float* __restrict__ bnd,
                       unsigned* __restrict__ maxk)
{
    const int s = blockIdx.x, h = blockIdx.y, b = blockIdx.z, d = threadIdx.x;
    const int wave = d >> 6;
    __shared__ float row[128];
    __shared__ float sred[2][3];

    const float* qrow = qkv + (size_t)(b * SEQ + s) * QKV_N;
    float qv = qrow[h * 128 + d];
    float sqv = sigma_f(qv);
    sq[((size_t)(b * NH + h) * SEQ + s) * 128 + d] = (__bf16)sqv;
    float nds = sqv * norm_in[(b * NKV + (h & 7)) * 128 + d];

    row[d] = qv;
    __syncthreads();
    // RoPE angles
    const int pos = pos_ids[s];
    const int j = d & 63;
    float inv = __expf(-((float)(2 * j) / 128.f) * 9.210340371976184f); // ln(10000)
    float ang = (float)pos * inv;
    float c, sn;
    __sincosf(ang, &sn, &c);
    const float scale = 0.08838834764831845f;   // 1/sqrt(128), folded into q
    float rot = (d < 64) ? -row[d + 64] : row[d - 64];
    float qq = (qv * c + rot * sn) * scale;
    qr[((size_t)(b * NH + h) * SEQ + s) * 128 + d] = (__bf16)qq;
    float qns = qq * qq;

    float kns = 0.f;
    if (h < NKV) {
        float kv = qrow[2048 + h * 128 + d];
        float vv = qrow[3072 + h * 128 + d];
        __syncthreads();
        row[d] = kv;
        __syncthreads();
        float rotk = (d < 64) ? -row[d + 64] : row[d - 64];
        float kk = kv * c + rotk * sn;
        kr[((size_t)(b * NKV + h) * SEQ + s) * 128 + d] = (__bf16)kk;
        vt[((size_t)((b * NKV + h) * 128 + d)) * SEQ + s] = (__bf16)vv;
        kns = kk * kk;
    }

    // three wave-level reductions then cross-wave combine
    #pragma unroll
    for (int off = 32; off > 0; off >>= 1) {
        nds += __shfl_down(nds, off);
        qns += __shfl_down(qns, off);
        kns += __shfl_down(kns, off);
    }
    if ((d & 63) == 0) { sred[wave][0] = nds; sred[wave][1] = qns; sred[wave][2] = kns; }
    __syncthreads();
    if (d == 0) {
        nd [(size_t)(b * NH + h) * SEQ + s] = sred[0][0] + sred[1][0];
        bnd[(size_t)(b * NH + h) * SEQ + s] = sred[0][1] + sred[1][1];
        if (h < NKV) {
            float kn2 = sred[0][2] + sred[1][2];
            atomicMax(&maxk[b * NKV + h], __float_as_uint(kn2));
        }
    }
}

// =====================================================================
// K3: memory_output = (sigma_q @ mem) / nd, write g*val into combined
// =====================================================================
__global__ __launch_bounds__(256) void memout_k(const __bf16* __restrict__ sq,
                                                const float* __restrict__ mem_in,
                                                const float* __restrict__ nd,
                                                const float* __restrict__ gate,
                                                __bf16* __restrict__ cb)
{
    __shared__ __align__(16) __bf16 mt[128][136];   // mem^T [e][d]
    const int tid = threadIdx.x;
    const int h = blockIdx.y, b = blockIdx.z;
    const int s0 = blockIdx.x * 64;

    const float* mem = mem_in + (size_t)(b * NKV + (h & 7)) * 16384;
    for (int i = tid; i < 16384; i += 256) {
        int dd = i >> 7, e = i & 127;
        mt[e][dd] = (__bf16)mem[i];
    }
    __syncthreads();

    const int wave = tid >> 6, lane = tid & 63, l15 = lane & 15, l4 = lane >> 4;
    f32x4 acc[8] = {};
    const __bf16* sqb = sq + ((size_t)(b * NH + h) * SEQ + s0 + wave * 16 + l15) * 128;
    #pragma unroll
    for (int kb = 0; kb < 4; ++kb) {
        bf16x8 a = *reinterpret_cast<const bf16x8*>(sqb + kb * 32 + l4 * 8);
        #pragma unroll
        for (int nc = 0; nc < 8; ++nc) {
            bf16x8 bb = *reinterpret_cast<bf16x8*>(&mt[nc * 16 + l15][kb * 32 + l4 * 8]);
            acc[nc] = mfma16(a, bb, acc[nc]);
        }
    }
    float g = 1.f / (1.f + __expf(-gate[h]));
    #pragma unroll
    for (int r = 0; r < 4; ++r) {
        int srow = s0 + wave * 16 + l4 * 4 + r;
        float scl = g / nd[(size_t)(b * NH + h) * SEQ + srow];
        __bf16* cbp = cb + (size_t)(b * SEQ + srow) * HID + h * 128;
        #pragma unroll
        for (int nc = 0; nc < 8; ++nc)
            cbp[nc * 16 + l15] = (__bf16)(acc[nc][r] * scl);
    }
}

// =====================================================================
// K4: updated_norm = norm_in + sum_s sigma_k
// =====================================================================
__global__ void normupd_k(const float* __restrict__ qkv, const float* __restrict__ norm_in,
                          float* __restrict__ out_norm)
{
    const int h = blockIdx.x, b = blockIdx.y;
    const int t = threadIdx.x, d = t & 127, sg = t >> 7;   // 512 threads: 4 s-groups
    __shared__ float pr[4][128];
    float acc = 0.f;
    for (int s = sg; s < SEQ; s += 4) {
        float kv = qkv[(size_t)(b * SEQ + s) * QKV_N + 2048 + h * 128 + d];
        acc += sigma_f(kv);
    }
    pr[sg][d] = acc;
    __syncthreads();
    if (sg == 0)
        out_norm[(b * NKV + h) * 128 + d] =
            norm_in[(b * NKV + h) * 128 + d] + pr[0][d] + pr[1][d] + pr[2][d] + pr[3][d];
}

// =====================================================================
// K5: updated_memory partials: part[sp] = sigma_k^T @ v over s-chunk
// =====================================================================
__global__ __launch_bounds__(256) void memupd_k(const float* __restrict__ qkv,
                                                float* __restrict__ part)
{
    const int sp = blockIdx.x, h = blockIdx.y, b = blockIdx.z;
    const int tid = threadIdx.x;
    const int tx = tid & 15, ty = tid >> 4;   // d-block tx*8, e-block ty*8
    __shared__ __align__(16) float sk[8][128];
    __shared__ __align__(16) float sv[8][128];
    float acc[8][8] = {};

    const int s0 = sp * (SEQ / NSPLIT);
    for (int so = 0; so < SEQ / NSPLIT; so += 8) {
        for (int i = tid; i < 8 * 128; i += 256) {
            int rr = i >> 7, dd = i & 127;
            const float* rowp = qkv + (size_t)(b * SEQ + s0 + so + rr) * QKV_N;
            sk[rr][dd] = sigma_f(rowp[2048 + h * 128 + dd]);
            sv[rr][dd] = rowp[3072 + h * 128 + dd];
        }
        __syncthreads();
        #pragma unroll
        for (int rr = 0; rr < 8; ++rr) {
            float4 k0 = *reinterpret_cast<float4*>(&sk[rr][tx * 8]);
            float4 k1 = *reinterpret_cast<float4*>(&sk[rr][tx * 8 + 4]);
            float4 v0 = *reinterpret_cast<float4*>(&sv[rr][ty * 8]);
            float4 v1 = *reinterpret_cast<float4*>(&sv[rr][ty * 8 + 4]);
            float kreg[8] = {k0.x,k0.y,k0.z,k0.w,k1.x,k1.y,k1.z,k1.w};
            float vreg[8] = {v0.x,v0.y,v0.z,v0.w,v1.x,v1.y,v1.z,v1.w};
            #pragma unroll
            for (int i = 0; i < 8; ++i)
                #pragma unroll
                for (int j2 = 0; j2 < 8; ++j2)
                    acc[i][j2] += kreg[i] * vreg[j2];
        }
        __syncthreads();
    }
    float* pb = part + ((size_t)sp * (BATCH * NKV) + b * NKV + h) * 16384;
    #pragma unroll
    for (int i = 0; i < 8; ++i)
        #pragma unroll
        for (int j2 = 0; j2 < 8; ++j2)
            pb[(tx * 8 + i) * 128 + ty * 8 + j2] = acc[i][j2];
}

// K6: reduce partials + memory_in
__global__ void memred_k(const float* __restrict__ part, const float* __restrict__ mem_in,
                         float* __restrict__ out_mem)
{
    const size_t i = (size_t)blockIdx.x * 256 + threadIdx.x;   // 262144 total
    float a = mem_in[i];
    #pragma unroll
    for (int sp = 0; sp < NSPLIT; ++sp) a += part[(size_t)sp * 262144 + i];
    out_mem[i] = a;
}

// =====================================================================
// K7: flash causal attention — fixed-bound softmax (no shuffles, no
// rescale): m = ||q||*max||k||+1 >= any score (Cauchy-Schwarz, RoPE is a
// rotation). li accumulated via MFMA against a ones B-fragment.
// Balanced q-tile pairs; K/V staged in LDS.
// =====================================================================
__global__ __launch_bounds__(256) void attn_k(const __bf16* __restrict__ qr,
                                              const __bf16* __restrict__ kr,
                                              const __bf16* __restrict__ vt,
                                              const float* __restrict__ gate,
                                              const float* __restrict__ bnd,
                                              const unsigned* __restrict__ maxk,
                                              __bf16* __restrict__ cb)
{
    __shared__ __align__(16) __bf16 Ks[64][136];    // [key][d]   (+8 pad)
    __shared__ __align__(16) __bf16 Vs[128][72];    // [d][key]   (+8 pad)
    __shared__ __align__(16) __bf16 plds[4][16][72];// per-wave P transpose

    const int tid = threadIdx.x, wave = tid >> 6, lane = tid & 63;
    const int l15 = lane & 15, l4 = lane >> 4;
    const int h = blockIdx.y, b = blockIdx.z;
    const int kvh = h >> 1;

    const __bf16* kbase = kr + (size_t)(b * NKV + kvh) * SEQ * 128;
    const __bf16* vbase = vt + (size_t)(b * NKV + kvh) * 128 * SEQ;
    const float* bbase  = bnd + (size_t)(b * NH + h) * SEQ;

    const float g  = 1.f / (1.f + __expf(-gate[h]));
    const float gi = 1.f - g;
    const float knmax = sqrtf(__uint_as_float(maxk[b * NKV + kvh]));

    bf16x8 ones;
    #pragma unroll
    for (int j = 0; j < 8; ++j) ones[j] = (__bf16)1.0f;

    const int k_row = tid >> 4, k_col = (tid & 15) * 8;   // K: 16 rows/round
    const int v_row = tid >> 3, v_col = (tid & 7) * 8;    // V: 32 rows/round

    #pragma unroll 1
    for (int tile = 0; tile < 2; ++tile) {
        const int q0 = (tile == 0 ? blockIdx.x : 31 - blockIdx.x) * 64;
        const int qw = q0 + wave * 16;

        const __bf16* qbase = qr + ((size_t)(b * NH + h) * SEQ + qw + l15) * 128;
        bf16x8 af[4];
        #pragma unroll
        for (int kb = 0; kb < 4; ++kb)
            af[kb] = *reinterpret_cast<const bf16x8*>(qbase + kb * 32 + l4 * 8);

        // fixed safe bound per q-row
        float m_r[4];
        #pragma unroll
        for (int r = 0; r < 4; ++r)
            m_r[r] = sqrtf(bbase[qw + l4 * 4 + r]) * knmax + 1.0f;

        f32x4 o[8] = {};
        f32x4 lacc = {};

        #pragma unroll 1
        for (int kt = 0; kt < q0 + 64; kt += 64) {
            // ---- cooperative staging of K (64x128) and V^T (128x64) ----
            #pragma unroll
            for (int r = 0; r < 4; ++r) {
                *reinterpret_cast<bf16x8*>(&Ks[r * 16 + k_row][k_col]) =
                    *reinterpret_cast<const bf16x8*>(kbase + (size_t)(kt + r * 16 + k_row) * 128 + k_col);
            }
            #pragma unroll
            for (int r = 0; r < 4; ++r) {
                *reinterpret_cast<bf16x8*>(&Vs[r * 32 + v_row][v_col]) =
                    *reinterpret_cast<const bf16x8*>(vbase + (size_t)(r * 32 + v_row) * SEQ + kt + v_col);
            }
            __syncthreads();

            // ---- QK^T ----
            f32x4 sv[4] = {};
            #pragma unroll
            for (int kb = 0; kb < 4; ++kb) {
                #pragma unroll
                for (int sub = 0; sub < 4; ++sub) {
                    bf16x8 bb = *reinterpret_cast<bf16x8*>(&Ks[sub * 16 + l15][kb * 32 + l4 * 8]);
                    sv[sub] = mfma16(af[kb], bb, sv[sub]);
                }
            }

            // ---- exp with fixed bound, causal mask, store P ----
            #pragma unroll
            for (int r = 0; r < 4; ++r) {
                const int qrow = qw + l4 * 4 + r;
                #pragma unroll
                for (int sub = 0; sub < 4; ++sub) {
                    const int key = kt + sub * 16 + l15;
                    float p = __expf(sv[sub][r] - m_r[r]);
                    p = (key <= qrow) ? p : 0.f;
                    plds[wave][l4 * 4 + r][sub * 16 + l15] = (__bf16)p;
                }
            }

            // ---- PV + row-sum via ones-fragment ----
            bf16x8 ap0 = *reinterpret_cast<bf16x8*>(&plds[wave][l15][l4 * 8]);
            bf16x8 ap1 = *reinterpret_cast<bf16x8*>(&plds[wave][l15][32 + l4 * 8]);
            lacc = mfma16(ap0, ones, lacc);
            lacc = mfma16(ap1, ones, lacc);
            #pragma unroll
            for (int nc = 0; nc < 8; ++nc) {
                bf16x8 b0 = *reinterpret_cast<bf16x8*>(&Vs[nc * 16 + l15][l4 * 8]);
                bf16x8 b1 = *reinterpret_cast<bf16x8*>(&Vs[nc * 16 + l15][32 + l4 * 8]);
                o[nc] = mfma16(ap0, b0, o[nc]);
                o[nc] = mfma16(ap1, b1, o[nc]);
            }
            __syncthreads();
        }

        // ---- epilogue: add (1-g) * attn / li into combined ----
        #pragma unroll
        for (int r = 0; r < 4; ++r) {
            const int qrow = qw + l4 * 4 + r;
            const float inv = gi / lacc[r];
            __bf16* cbp = cb + (size_t)(b * SEQ + qrow) * HID + h * 128;
            #pragma unroll
            for (int nc = 0; nc < 8; ++nc) {
                const int dd = nc * 16 + l15;
                float prev = (float)cbp[dd];
                cbp[dd] = (__bf16)(prev + o[nc][r] * inv);
            }
        }
    }
}

// =====================================================================
extern "C" void kernel_launch(void* const* d_in, const int* in_sizes, int n_in,
                              void* d_out, int out_size, void* d_ws, size_t ws_size,
                              hipStream_t stream)
{
    const float* hidden  = (const float*)d_in[0];
    const float* Wq      = (const float*)d_in[1];
    const float* Wk      = (const float*)d_in[2];
    const float* Wv      = (const float*)d_in[3];
    const float* Wo      = (const float*)d_in[4];
    const float* gate    = (const float*)d_in[5];
    const float* mem_in  = (const float*)d_in[6];
    const float* norm_in = (const float*)d_in[7];
    const int*   pos     = (const int*)d_in[8];

    float* out_final = (float*)d_out;                  // (B,S,HID)
    float* out_mem   = out_final + (size_t)BATCH * SEQ * HID;     // (B,8,128,128)
    float* out_norm  = out_mem + (size_t)BATCH * NKV * 128 * 128; // (B,8,1,128)

    char* ws = (char*)d_ws;
    float*  qkv  = (float*)(ws + OFF_QKV);
    __bf16* sq   = (__bf16*)(ws + OFF_SQ);
    __bf16* qrb  = (__bf16*)(ws + OFF_QR);
    __bf16* krb  = (__bf16*)(ws + OFF_KR);
    __bf16* vtb  = (__bf16*)(ws + OFF_VT);
    float*  nd   = (float*)(ws + OFF_ND);
    __bf16* cb   = (__bf16*)(ws + OFF_CB);
    float*  part = (float*)(ws + OFF_PART);
    float*  bnd  = (float*)(ws + OFF_BND);
    unsigned* maxk = (unsigned*)(ws + OFF_MAXK);
    // overlays (lifetimes disjoint from the named owners):
    __bf16* hb   = (__bf16*)(ws + OFF_SQ);    // bf16 hidden  [4096][2048], dead after gemm1
    __bf16* qkvT = (__bf16*)(ws + OFF_QR);    // bf16 W_qkv^T [4096][2048], dead after gemm1
    __bf16* woT  = (__bf16*)(ws + OFF_PART);  // bf16 Wo^T    [2048][2048], after memred

    // 0. bf16 conversions / weight transposes; zero the atomicMax scratch
    hipMemsetAsync(maxk, 0, BATCH * NKV * sizeof(unsigned), stream);
    f2b_k<<<(M_ROWS * HID) / (256 * 8), 256, 0, stream>>>(hidden, hb);
    tr_k<<<dim3(HID / 64, 2048 / 64), 256, 0, stream>>>(Wq, qkvT, HID, 2048);
    tr_k<<<dim3(HID / 64, 1024 / 64), 256, 0, stream>>>(Wk, qkvT + (size_t)2048 * HID, HID, 1024);
    tr_k<<<dim3(HID / 64, 1024 / 64), 256, 0, stream>>>(Wv, qkvT + (size_t)3072 * HID, HID, 1024);

    // 1. fused QKV projection: [4096 x 2048] @ [2048 x 4096]
    gemm_bt<<<dim3(M_ROWS / 128, QKV_N / 128), 256, 0, stream>>>(hb, qkvT, qkv, QKV_N, HID);

    // 2. sigma_q / norm-dot / RoPE / V^T / norms  (overwrites hb/qkvT — now dead)
    prep_k<<<dim3(SEQ, NH, BATCH), 128, 0, stream>>>(qkv, norm_in, pos, sq, qrb, krb, vtb,
                                                     nd, bnd, maxk);

    // 3. memory_output -> combined (g * memout / nd)
    memout_k<<<dim3(SEQ / 64, NH, BATCH), 256, 0, stream>>>(sq, mem_in, nd, gate, cb);

    // 4. updated_norm
    normupd_k<<<dim3(NKV, BATCH), 512, 0, stream>>>(qkv, norm_in, out_norm);

    // 5/6. updated_memory
    memupd_k<<<dim3(NSPLIT, NKV, BATCH), 256, 0, stream>>>(qkv, part);
    memred_k<<<(BATCH * NKV * 128 * 128) / 256, 256, 0, stream>>>(part, mem_in, out_mem);

    // 6b. Wo^T (overlays part — dead after memred)
    tr_k<<<dim3(HID / 64, HID / 64), 256, 0, stream>>>(Wo, woT, HID, HID);

    // 7. causal attention (fixed-bound softmax), adds (1-g)*attn into combined
    attn_k<<<dim3(16, NH, BATCH), 256, 0, stream>>>(qrb, krb, vtb, gate, bnd, maxk, cb);

    // 8. output projection: [4096 x 2048] @ [2048 x 2048]
    gemm_bt<<<dim3(M_ROWS / 128, HID / 128), 256, 0, stream>>>(cb, woT, out_final, HID, HID);
}

// Round 5
// 671.505 us; speedup vs baseline: 1.5236x; 1.5236x over previous
//
#include <hip/hip_runtime.h>

// ---------- problem constants ----------
#define BATCH 2
#define SEQ   2048
#define HID   2048
#define NH    16
#define NKV   8
#define HD    128
#define M_ROWS (BATCH * SEQ)          // 4096
#define QKV_N  4096                   // 2048 q | 1024 k | 1024 v

typedef __attribute__((ext_vector_type(8))) __bf16 bf16x8;
typedef __attribute__((ext_vector_type(4))) float  f32x4;

static __device__ __forceinline__ f32x4 mfma16(bf16x8 a, bf16x8 b, f32x4 c) {
    return __builtin_amdgcn_mfma_f32_16x16x32_bf16(a, b, c, 0, 0, 0);
}
static __device__ __forceinline__ float sigma_f(float x) {
    return x > 0.f ? x + 1.f : __expf(x);   // elu(x)+1
}
// async global->LDS, 16B per lane; lds base must be wave-uniform
static __device__ __forceinline__ void gload16(const __bf16* g, __bf16* l) {
    __builtin_amdgcn_global_load_lds(
        (const __attribute__((address_space(1))) void*)g,
        (__attribute__((address_space(3))) void*)l, 16, 0, 0);
}

// ---------- workspace layout (bytes) ----------
#define OFF_QKV  0ull                              // float [4096][4096]   64 MB
#define OFF_SQ   67108864ull                       // bf16  (b,h,S,128)    16 MB  (pre-GEMM: hb)
#define OFF_QR   83886080ull                       // bf16  (b,h,S,128)    16 MB  (pre-GEMM: qkvT)
#define OFF_KR   100663296ull                      // bf16  (b,kvh,S,128)   8 MB
#define OFF_VT   109051904ull                      // bf16  (b,kvh,128,S)   8 MB
#define OFF_ND   117440512ull                      // float (b,h,S)       256 KB
#define OFF_CB   117702656ull                      // bf16  [4096][2048]   16 MB
#define OFF_PART 134479872ull                      // float 8*(b,kvh,128,128) 8 MB (late: woT 8 MB)
#define OFF_BND  142868480ull                      // float (b,h,S)       256 KB  (q row-norm^2)
#define OFF_MAXP 143130624ull                      // float (b,kvh,8)     512 B   (k-norm^2 partial max)
#define NSPLIT 8

// =====================================================================
// K0a: fp32 -> bf16 bulk convert (8 elems/thread)
// =====================================================================
__global__ void f2b_k(const float* __restrict__ src, __bf16* __restrict__ dst)
{
    const size_t i = ((size_t)blockIdx.x * 256 + threadIdx.x) * 8;
    const float4 v0 = *reinterpret_cast<const float4*>(src + i);
    const float4 v1 = *reinterpret_cast<const float4*>(src + i + 4);
    bf16x8 t;
    t[0]=(__bf16)v0.x; t[1]=(__bf16)v0.y; t[2]=(__bf16)v0.z; t[3]=(__bf16)v0.w;
    t[4]=(__bf16)v1.x; t[5]=(__bf16)v1.y; t[6]=(__bf16)v1.z; t[7]=(__bf16)v1.w;
    *reinterpret_cast<bf16x8*>(dst + i) = t;
}

// =====================================================================
// K0b: W fp32 [K][N] -> Bt bf16 [N][K]  (64x64 LDS tile transpose)
// =====================================================================
__global__ __launch_bounds__(256) void tr_k(const float* __restrict__ W,
                                            __bf16* __restrict__ Bt, int K, int N)
{
    __shared__ __bf16 T[64][72];
    const int k0 = blockIdx.x * 64, n0 = blockIdx.y * 64;
    const int t = threadIdx.x;
    #pragma unroll
    for (int i = 0; i < 4; ++i) {
        const int idx = t + i * 256;           // 0..1023
        const int r = idx >> 4, c4 = (idx & 15) * 4;
        const float4 v = *reinterpret_cast<const float4*>(&W[(size_t)(k0 + r) * N + n0 + c4]);
        T[c4 + 0][r] = (__bf16)v.x; T[c4 + 1][r] = (__bf16)v.y;
        T[c4 + 2][r] = (__bf16)v.z; T[c4 + 3][r] = (__bf16)v.w;
    }
    __syncthreads();
    #pragma unroll
    for (int i = 0; i < 2; ++i) {
        const int idx = t + i * 256;           // 0..511
        const int rr = idx >> 3, cc = (idx & 7) * 8;
        *reinterpret_cast<bf16x8*>(&Bt[(size_t)(n0 + rr) * K + k0 + cc]) =
            *reinterpret_cast<bf16x8*>(&T[rr][cc]);
    }
}

// =====================================================================
// K1 / K8: m97-style GEMM. C[M][N] = A[M][K] @ Bt[N][K]^T, fp32 out.
// 128x128 tile, BK=32, global_load_lds width-16 staging.
// =====================================================================
__global__ __launch_bounds__(256) void gemm_bt(const __bf16* __restrict__ A,
                                               const __bf16* __restrict__ Bt,
                                               float* __restrict__ C,
                                               int N, int K)
{
    __shared__ __align__(16) __bf16 As[128 * 32];
    __shared__ __align__(16) __bf16 Bs[128 * 32];

    const int tid = threadIdx.x, wave = tid >> 6, lane = tid & 63;
    const int l15 = lane & 15, l4 = lane >> 4;
    const int m0 = blockIdx.x * 128, n0 = blockIdx.y * 128;
    const int wm = (wave & 1) * 64, wn = (wave >> 1) * 64;

    f32x4 acc[4][4] = {};

    const int srow = wave * 32 + (lane >> 2);
    const int scol = (lane & 3) * 8;
    const __bf16* Ab = A  + (size_t)(m0 + srow) * K + scol;
    const __bf16* Bb = Bt + (size_t)(n0 + srow) * K + scol;
    __bf16* AsB0 = &As[(wave * 32) * 32];
    __bf16* AsB1 = &As[(wave * 32 + 16) * 32];
    __bf16* BsB0 = &Bs[(wave * 32) * 32];
    __bf16* BsB1 = &Bs[(wave * 32 + 16) * 32];

    for (int kb = 0; kb < K; kb += 32) {
        gload16(Ab + kb,            AsB0);
        gload16(Ab + 16 * K + kb,   AsB1);
        gload16(Bb + kb,            BsB0);
        gload16(Bb + 16 * K + kb,   BsB1);
        __syncthreads();

        bf16x8 af[4], bfr[4];
        #pragma unroll
        for (int mt = 0; mt < 4; ++mt)
            af[mt] = *reinterpret_cast<bf16x8*>(&As[(wm + mt * 16 + l15) * 32 + l4 * 8]);
        #pragma unroll
        for (int nt = 0; nt < 4; ++nt)
            bfr[nt] = *reinterpret_cast<bf16x8*>(&Bs[(wn + nt * 16 + l15) * 32 + l4 * 8]);
        #pragma unroll
        for (int mt = 0; mt < 4; ++mt)
            #pragma unroll
            for (int nt = 0; nt < 4; ++nt)
                acc[mt][nt] = mfma16(af[mt], bfr[nt], acc[mt][nt]);
        __syncthreads();
    }

    #pragma unroll
    for (int mt = 0; mt < 4; ++mt)
        #pragma unroll
        for (int nt = 0; nt < 4; ++nt)
            #pragma unroll
            for (int r = 0; r < 4; ++r) {
                const int row = m0 + wm + mt * 16 + l4 * 4 + r;
                const int col = n0 + wn + nt * 16 + l15;
                C[(size_t)row * N + col] = acc[mt][nt][r];
            }
}

// =====================================================================
// K2: prep v2 — grid (SEQ/32, NKV, BATCH), 256 threads.
// Per block: 32 s-rows of one kv-group. Q heads 2kvh,2kvh+1: sigma->sq,
// RoPE*scale->qr, nd=sq.norm dot, bnd=||q||^2*scale^2 (rotation preserves
// norm). K head: RoPE->kr. V head: LDS-transpose -> vt (coalesced).
// No atomics.
// =====================================================================
__global__ __launch_bounds__(256) void prep_k(const float* __restrict__ qkv,
                                              const float* __restrict__ norm_in,
                                              const int* __restrict__ pos_ids,
                                              __bf16* __restrict__ sq, __bf16* __restrict__ qr,
                                              __bf16* __restrict__ kr, __bf16* __restrict__ vt,
                                              float* __restrict__ nd, float* __restrict__ bnd)
{
    const int sc = blockIdx.x, kvh = blockIdx.y, b = blockIdx.z;
    const int s0 = sc * 32, t = threadIdx.x;
    const float scale = 0.08838834764831845f;      // 1/sqrt(128)
    const float s2 = scale * scale;
    const float NEG_LN_TH = -0.14391156831212787f; // -ln(10000)/64

    // ---------- Q phase: 64 rows (2 heads x 32 s), 4 threads/row ----------
    {
        const int row = t >> 2;             // 0..63
        const int head = row >> 5, sl = row & 31;
        const int hq = kvh * 2 + head, nh = hq & 7;
        const int dq = (t & 3) * 16;        // pair-halves [dq,dq+16) & [dq+64,dq+80)
        const int pos = pos_ids[s0 + sl];
        const float* qp = qkv + (size_t)(b * SEQ + s0 + sl) * QKV_N + hq * 128;
        const float* np = norm_in + (b * NKV + nh) * 128;

        float x0[16], x1[16];
        #pragma unroll
        for (int i = 0; i < 16; i += 4) {
            *reinterpret_cast<float4*>(&x0[i]) = *reinterpret_cast<const float4*>(qp + dq + i);
            *reinterpret_cast<float4*>(&x1[i]) = *reinterpret_cast<const float4*>(qp + dq + 64 + i);
        }
        float nds = 0.f, qns = 0.f;
        bf16x8 sqv0[2], sqv1[2], qrv0[2], qrv1[2];
        #pragma unroll
        for (int i = 0; i < 16; ++i) {
            const int j = dq + i;           // 0..63
            float c, sn;
            __sincosf((float)pos * __expf((float)j * NEG_LN_TH), &sn, &c);
            qrv0[i >> 3][i & 7] = (__bf16)((x0[i] * c - x1[i] * sn) * scale);
            qrv1[i >> 3][i & 7] = (__bf16)((x1[i] * c + x0[i] * sn) * scale);
            const float sg0 = sigma_f(x0[i]), sg1 = sigma_f(x1[i]);
            sqv0[i >> 3][i & 7] = (__bf16)sg0;
            sqv1[i >> 3][i & 7] = (__bf16)sg1;
            nds += sg0 * np[j] + sg1 * np[j + 64];
            qns += (x0[i] * x0[i] + x1[i] * x1[i]) * s2;
        }
        __bf16* sqp = sq + ((size_t)(b * NH + hq) * SEQ + s0 + sl) * 128;
        __bf16* qrp = qr + ((size_t)(b * NH + hq) * SEQ + s0 + sl) * 128;
        *reinterpret_cast<bf16x8*>(sqp + dq)      = sqv0[0];
        *reinterpret_cast<bf16x8*>(sqp + dq + 8)  = sqv0[1];
        *reinterpret_cast<bf16x8*>(sqp + dq + 64) = sqv1[0];
        *reinterpret_cast<bf16x8*>(sqp + dq + 72) = sqv1[1];
        *reinterpret_cast<bf16x8*>(qrp + dq)      = qrv0[0];
        *reinterpret_cast<bf16x8*>(qrp + dq + 8)  = qrv0[1];
        *reinterpret_cast<bf16x8*>(qrp + dq + 64) = qrv1[0];
        *reinterpret_cast<bf16x8*>(qrp + dq + 72) = qrv1[1];

        nds += __shfl_xor(nds, 1); nds += __shfl_xor(nds, 2);
        qns += __shfl_xor(qns, 1); qns += __shfl_xor(qns, 2);
        if ((t & 3) == 0) {
            nd [(size_t)(b * NH + hq) * SEQ + s0 + sl] = nds;
            bnd[(size_t)(b * NH + hq) * SEQ + s0 + sl] = qns;
        }
    }

    // ---------- K phase: 32 rows, 4 threads/row (threads 0..127) ----------
    if (t < 128) {
        const int sl = t >> 2;
        const int dq = (t & 3) * 16;
        const int pos = pos_ids[s0 + sl];
        const float* kp = qkv + (size_t)(b * SEQ + s0 + sl) * QKV_N + 2048 + kvh * 128;
        float x0[16], x1[16];
        #pragma unroll
        for (int i = 0; i < 16; i += 4) {
            *reinterpret_cast<float4*>(&x0[i]) = *reinterpret_cast<const float4*>(kp + dq + i);
            *reinterpret_cast<float4*>(&x1[i]) = *reinterpret_cast<const float4*>(kp + dq + 64 + i);
        }
        bf16x8 kv0[2], kv1[2];
        #pragma unroll
        for (int i = 0; i < 16; ++i) {
            const int j = dq + i;
            float c, sn;
            __sincosf((float)pos * __expf((float)j * NEG_LN_TH), &sn, &c);
            kv0[i >> 3][i & 7] = (__bf16)(x0[i] * c - x1[i] * sn);
            kv1[i >> 3][i & 7] = (__bf16)(x1[i] * c + x0[i] * sn);
        }
        __bf16* krp = kr + ((size_t)(b * NKV + kvh) * SEQ + s0 + sl) * 128;
        *reinterpret_cast<bf16x8*>(krp + dq)      = kv0[0];
        *reinterpret_cast<bf16x8*>(krp + dq + 8)  = kv0[1];
        *reinterpret_cast<bf16x8*>(krp + dq + 64) = kv1[0];
        *reinterpret_cast<bf16x8*>(krp + dq + 72) = kv1[1];
    }

    // ---------- V phase: transpose via LDS, coalesced vt writes ----------
    __shared__ float vl[128][33];
    {
        const int sl = t >> 3, dch = (t & 7) * 16;
        const float* vp = qkv + (size_t)(b * SEQ + s0 + sl) * QKV_N + 3072 + kvh * 128 + dch;
        float xv[16];
        #pragma unroll
        for (int i = 0; i < 16; i += 4)
            *reinterpret_cast<float4*>(&xv[i]) = *reinterpret_cast<const float4*>(vp + i);
        #pragma unroll
        for (int i = 0; i < 16; ++i) vl[dch + i][sl] = xv[i];
    }
    __syncthreads();
    {
        const int d = t >> 1, sh = (t & 1) * 16;
        bf16x8 o0, o1;
        #pragma unroll
        for (int j = 0; j < 8; ++j) o0[j] = (__bf16)vl[d][sh + j];
        #pragma unroll
        for (int j = 0; j < 8; ++j) o1[j] = (__bf16)vl[d][sh + 8 + j];
        __bf16* vp = vt + ((size_t)((b * NKV + kvh) * 128 + d)) * SEQ + s0 + sh;
        *reinterpret_cast<bf16x8*>(vp)     = o0;
        *reinterpret_cast<bf16x8*>(vp + 8) = o1;
    }
}

// =====================================================================
// K2b: per-(b,kvh) partial max of ||k_row||^2 over s-chunks of 256.
// RoPE preserves row norms, so raw k suffices. No atomics.
// =====================================================================
__global__ __launch_bounds__(256) void kmax_k(const float* __restrict__ qkv,
                                              float* __restrict__ maxp)
{
    const int sc = blockIdx.x, kvh = blockIdx.y, b = blockIdx.z;
    const int t = threadIdx.x;
    const int s = sc * 256 + t;
    const float* kp = qkv + (size_t)(b * SEQ + s) * QKV_N + 2048 + kvh * 128;
    float sum = 0.f;
    #pragma unroll
    for (int i = 0; i < 128; i += 4) {
        const float4 v = *reinterpret_cast<const float4*>(kp + i);
        sum += v.x * v.x + v.y * v.y + v.z * v.z + v.w * v.w;
    }
    #pragma unroll
    for (int off = 32; off > 0; off >>= 1) sum = fmaxf(sum, __shfl_xor(sum, off));
    __shared__ float wm[4];
    if ((t & 63) == 0) wm[t >> 6] = sum;
    __syncthreads();
    if (t == 0)
        maxp[(b * NKV + kvh) * 8 + sc] = fmaxf(fmaxf(wm[0], wm[1]), fmaxf(wm[2], wm[3]));
}

// =====================================================================
// K3: memory_output = (sigma_q @ mem) / nd, write g*val into combined
// =====================================================================
__global__ __launch_bounds__(256) void memout_k(const __bf16* __restrict__ sq,
                                                const float* __restrict__ mem_in,
                                                const float* __restrict__ nd,
                                                const float* __restrict__ gate,
                                                __bf16* __restrict__ cb)
{
    __shared__ __align__(16) __bf16 mt[128][136];   // mem^T [e][d]
    const int tid = threadIdx.x;
    const int h = blockIdx.y, b = blockIdx.z;
    const int s0 = blockIdx.x * 64;

    const float* mem = mem_in + (size_t)(b * NKV + (h & 7)) * 16384;
    for (int i = tid; i < 16384; i += 256) {
        int dd = i >> 7, e = i & 127;
        mt[e][dd] = (__bf16)mem[i];
    }
    __syncthreads();

    const int wave = tid >> 6, lane = tid & 63, l15 = lane & 15, l4 = lane >> 4;
    f32x4 acc[8] = {};
    const __bf16* sqb = sq + ((size_t)(b * NH + h) * SEQ + s0 + wave * 16 + l15) * 128;
    #pragma unroll
    for (int kb = 0; kb < 4; ++kb) {
        bf16x8 a = *reinterpret_cast<const bf16x8*>(sqb + kb * 32 + l4 * 8);
        #pragma unroll
        for (int nc = 0; nc < 8; ++nc) {
            bf16x8 bb = *reinterpret_cast<bf16x8*>(&mt[nc * 16 + l15][kb * 32 + l4 * 8]);
            acc[nc] = mfma16(a, bb, acc[nc]);
        }
    }
    float g = 1.f / (1.f + __expf(-gate[h]));
    #pragma unroll
    for (int r = 0; r < 4; ++r) {
        int srow = s0 + wave * 16 + l4 * 4 + r;
        float scl = g / nd[(size_t)(b * NH + h) * SEQ + srow];
        __bf16* cbp = cb + (size_t)(b * SEQ + srow) * HID + h * 128;
        #pragma unroll
        for (int nc = 0; nc < 8; ++nc)
            cbp[nc * 16 + l15] = (__bf16)(acc[nc][r] * scl);
    }
}

// =====================================================================
// K4: updated_norm = norm_in + sum_s sigma_k
// =====================================================================
__global__ void normupd_k(const float* __restrict__ qkv, const float* __restrict__ norm_in,
                          float* __restrict__ out_norm)
{
    const int h = blockIdx.x, b = blockIdx.y;
    const int t = threadIdx.x, d = t & 127, sg = t >> 7;   // 512 threads: 4 s-groups
    __shared__ float pr[4][128];
    float acc = 0.f;
    for (int s = sg; s < SEQ; s += 4) {
        float kv = qkv[(size_t)(b * SEQ + s) * QKV_N + 2048 + h * 128 + d];
        acc += sigma_f(kv);
    }
    pr[sg][d] = acc;
    __syncthreads();
    if (sg == 0)
        out_norm[(b * NKV + h) * 128 + d] =
            norm_in[(b * NKV + h) * 128 + d] + pr[0][d] + pr[1][d] + pr[2][d] + pr[3][d];
}

// =====================================================================
// K5: updated_memory partials: part[sp] = sigma_k^T @ v over s-chunk
// =====================================================================
__global__ __launch_bounds__(256) void memupd_k(const float* __restrict__ qkv,
                                                float* __restrict__ part)
{
    const int sp = blockIdx.x, h = blockIdx.y, b = blockIdx.z;
    const int tid = threadIdx.x;
    const int tx = tid & 15, ty = tid >> 4;   // d-block tx*8, e-block ty*8
    __shared__ __align__(16) float sk[8][128];
    __shared__ __align__(16) float sv[8][128];
    float acc[8][8] = {};

    const int s0 = sp * (SEQ / NSPLIT);
    for (int so = 0; so < SEQ / NSPLIT; so += 8) {
        for (int i = tid; i < 8 * 128; i += 256) {
            int rr = i >> 7, dd = i & 127;
            const float* rowp = qkv + (size_t)(b * SEQ + s0 + so + rr) * QKV_N;
            sk[rr][dd] = sigma_f(rowp[2048 + h * 128 + dd]);
            sv[rr][dd] = rowp[3072 + h * 128 + dd];
        }
        __syncthreads();
        #pragma unroll
        for (int rr = 0; rr < 8; ++rr) {
            float4 k0 = *reinterpret_cast<float4*>(&sk[rr][tx * 8]);
            float4 k1 = *reinterpret_cast<float4*>(&sk[rr][tx * 8 + 4]);
            float4 v0 = *reinterpret_cast<float4*>(&sv[rr][ty * 8]);
            float4 v1 = *reinterpret_cast<float4*>(&sv[rr][ty * 8 + 4]);
            float kreg[8] = {k0.x,k0.y,k0.z,k0.w,k1.x,k1.y,k1.z,k1.w};
            float vreg[8] = {v0.x,v0.y,v0.z,v0.w,v1.x,v1.y,v1.z,v1.w};
            #pragma unroll
            for (int i = 0; i < 8; ++i)
                #pragma unroll
                for (int j2 = 0; j2 < 8; ++j2)
                    acc[i][j2] += kreg[i] * vreg[j2];
        }
        __syncthreads();
    }
    float* pb = part + ((size_t)sp * (BATCH * NKV) + b * NKV + h) * 16384;
    #pragma unroll
    for (int i = 0; i < 8; ++i)
        #pragma unroll
        for (int j2 = 0; j2 < 8; ++j2)
            pb[(tx * 8 + i) * 128 + ty * 8 + j2] = acc[i][j2];
}

// K6: reduce partials + memory_in
__global__ void memred_k(const float* __restrict__ part, const float* __restrict__ mem_in,
                         float* __restrict__ out_mem)
{
    const size_t i = (size_t)blockIdx.x * 256 + threadIdx.x;   // 262144 total
    float a = mem_in[i];
    #pragma unroll
    for (int sp = 0; sp < NSPLIT; ++sp) a += part[(size_t)sp * 262144 + i];
    out_mem[i] = a;
}

// =====================================================================
// K7: flash causal attention — fixed-bound softmax (no shuffles, no
// rescale): m = ||q||*max||k||+1 >= any score (Cauchy-Schwarz, RoPE is a
// rotation). li accumulated via MFMA against a ones B-fragment.
// Balanced q-tile pairs; K/V staged in LDS.
// =====================================================================
__global__ __launch_bounds__(256) void attn_k(const __bf16* __restrict__ qr,
                                              const __bf16* __restrict__ kr,
                                              const __bf16* __restrict__ vt,
                                              const float* __restrict__ gate,
                                              const float* __restrict__ bnd,
                                              const float* __restrict__ maxp,
                                              __bf16* __restrict__ cb)
{
    __shared__ __align__(16) __bf16 Ks[64][136];    // [key][d]   (+8 pad)
    __shared__ __align__(16) __bf16 Vs[128][72];    // [d][key]   (+8 pad)
    __shared__ __align__(16) __bf16 plds[4][16][72];// per-wave P transpose

    const int tid = threadIdx.x, wave = tid >> 6, lane = tid & 63;
    const int l15 = lane & 15, l4 = lane >> 4;
    const int h = blockIdx.y, b = blockIdx.z;
    const int kvh = h >> 1;

    const __bf16* kbase = kr + (size_t)(b * NKV + kvh) * SEQ * 128;
    const __bf16* vbase = vt + (size_t)(b * NKV + kvh) * 128 * SEQ;
    const float* bbase  = bnd + (size_t)(b * NH + h) * SEQ;

    const float g  = 1.f / (1.f + __expf(-gate[h]));
    const float gi = 1.f - g;
    float kn2 = 0.f;
    const float* mp = maxp + (b * NKV + kvh) * 8;
    #pragma unroll
    for (int i = 0; i < 8; ++i) kn2 = fmaxf(kn2, mp[i]);
    const float knmax = sqrtf(kn2);

    bf16x8 ones;
    #pragma unroll
    for (int j = 0; j < 8; ++j) ones[j] = (__bf16)1.0f;

    const int k_row = tid >> 4, k_col = (tid & 15) * 8;   // K: 16 rows/round
    const int v_row = tid >> 3, v_col = (tid & 7) * 8;    // V: 32 rows/round

    #pragma unroll 1
    for (int tile = 0; tile < 2; ++tile) {
        const int q0 = (tile == 0 ? blockIdx.x : 31 - blockIdx.x) * 64;
        const int qw = q0 + wave * 16;

        const __bf16* qbase = qr + ((size_t)(b * NH + h) * SEQ + qw + l15) * 128;
        bf16x8 af[4];
        #pragma unroll
        for (int kb = 0; kb < 4; ++kb)
            af[kb] = *reinterpret_cast<const bf16x8*>(qbase + kb * 32 + l4 * 8);

        // fixed safe bound per q-row
        float m_r[4];
        #pragma unroll
        for (int r = 0; r < 4; ++r)
            m_r[r] = sqrtf(bbase[qw + l4 * 4 + r]) * knmax + 1.0f;

        f32x4 o[8] = {};
        f32x4 lacc = {};

        #pragma unroll 1
        for (int kt = 0; kt < q0 + 64; kt += 64) {
            // ---- cooperative staging of K (64x128) and V^T (128x64) ----
            #pragma unroll
            for (int r = 0; r < 4; ++r) {
                *reinterpret_cast<bf16x8*>(&Ks[r * 16 + k_row][k_col]) =
                    *reinterpret_cast<const bf16x8*>(kbase + (size_t)(kt + r * 16 + k_row) * 128 + k_col);
            }
            #pragma unroll
            for (int r = 0; r < 4; ++r) {
                *reinterpret_cast<bf16x8*>(&Vs[r * 32 + v_row][v_col]) =
                    *reinterpret_cast<const bf16x8*>(vbase + (size_t)(r * 32 + v_row) * SEQ + kt + v_col);
            }
            __syncthreads();

            // ---- QK^T ----
            f32x4 sv[4] = {};
            #pragma unroll
            for (int kb = 0; kb < 4; ++kb) {
                #pragma unroll
                for (int sub = 0; sub < 4; ++sub) {
                    bf16x8 bb = *reinterpret_cast<bf16x8*>(&Ks[sub * 16 + l15][kb * 32 + l4 * 8]);
                    sv[sub] = mfma16(af[kb], bb, sv[sub]);
                }
            }

            // ---- exp with fixed bound, causal mask, store P ----
            #pragma unroll
            for (int r = 0; r < 4; ++r) {
                const int qrow = qw + l4 * 4 + r;
                #pragma unroll
                for (int sub = 0; sub < 4; ++sub) {
                    const int key = kt + sub * 16 + l15;
                    float p = __expf(sv[sub][r] - m_r[r]);
                    p = (key <= qrow) ? p : 0.f;
                    plds[wave][l4 * 4 + r][sub * 16 + l15] = (__bf16)p;
                }
            }

            // ---- PV + row-sum via ones-fragment ----
            bf16x8 ap0 = *reinterpret_cast<bf16x8*>(&plds[wave][l15][l4 * 8]);
            bf16x8 ap1 = *reinterpret_cast<bf16x8*>(&plds[wave][l15][32 + l4 * 8]);
            lacc = mfma16(ap0, ones, lacc);
            lacc = mfma16(ap1, ones, lacc);
            #pragma unroll
            for (int nc = 0; nc < 8; ++nc) {
                bf16x8 b0 = *reinterpret_cast<bf16x8*>(&Vs[nc * 16 + l15][l4 * 8]);
                bf16x8 b1 = *reinterpret_cast<bf16x8*>(&Vs[nc * 16 + l15][32 + l4 * 8]);
                o[nc] = mfma16(ap0, b0, o[nc]);
                o[nc] = mfma16(ap1, b1, o[nc]);
            }
            __syncthreads();
        }

        // ---- epilogue: add (1-g) * attn / li into combined ----
        #pragma unroll
        for (int r = 0; r < 4; ++r) {
            const int qrow = qw + l4 * 4 + r;
            const float inv = gi / lacc[r];
            __bf16* cbp = cb + (size_t)(b * SEQ + qrow) * HID + h * 128;
            #pragma unroll
            for (int nc = 0; nc < 8; ++nc) {
                const int dd = nc * 16 + l15;
                float prev = (float)cbp[dd];
                cbp[dd] = (__bf16)(prev + o[nc][r] * inv);
            }
        }
    }
}

// =====================================================================
extern "C" void kernel_launch(void* const* d_in, const int* in_sizes, int n_in,
                              void* d_out, int out_size, void* d_ws, size_t ws_size,
                              hipStream_t stream)
{
    const float* hidden  = (const float*)d_in[0];
    const float* Wq      = (const float*)d_in[1];
    const float* Wk      = (const float*)d_in[2];
    const float* Wv      = (const float*)d_in[3];
    const float* Wo      = (const float*)d_in[4];
    const float* gate    = (const float*)d_in[5];
    const float* mem_in  = (const float*)d_in[6];
    const float* norm_in = (const float*)d_in[7];
    const int*   pos     = (const int*)d_in[8];

    float* out_final = (float*)d_out;                  // (B,S,HID)
    float* out_mem   = out_final + (size_t)BATCH * SEQ * HID;     // (B,8,128,128)
    float* out_norm  = out_mem + (size_t)BATCH * NKV * 128 * 128; // (B,8,1,128)

    char* ws = (char*)d_ws;
    float*  qkv  = (float*)(ws + OFF_QKV);
    __bf16* sq   = (__bf16*)(ws + OFF_SQ);
    __bf16* qrb  = (__bf16*)(ws + OFF_QR);
    __bf16* krb  = (__bf16*)(ws + OFF_KR);
    __bf16* vtb  = (__bf16*)(ws + OFF_VT);
    float*  nd   = (float*)(ws + OFF_ND);
    __bf16* cb   = (__bf16*)(ws + OFF_CB);
    float*  part = (float*)(ws + OFF_PART);
    float*  bnd  = (float*)(ws + OFF_BND);
    float*  maxp = (float*)(ws + OFF_MAXP);
    // overlays (lifetimes disjoint from the named owners):
    __bf16* hb   = (__bf16*)(ws + OFF_SQ);    // bf16 hidden  [4096][2048], dead after gemm1
    __bf16* qkvT = (__bf16*)(ws + OFF_QR);    // bf16 W_qkv^T [4096][2048], dead after gemm1
    __bf16* woT  = (__bf16*)(ws + OFF_PART);  // bf16 Wo^T    [2048][2048], after memred

    // 0. bf16 conversions / weight transposes
    f2b_k<<<(M_ROWS * HID) / (256 * 8), 256, 0, stream>>>(hidden, hb);
    tr_k<<<dim3(HID / 64, 2048 / 64), 256, 0, stream>>>(Wq, qkvT, HID, 2048);
    tr_k<<<dim3(HID / 64, 1024 / 64), 256, 0, stream>>>(Wk, qkvT + (size_t)2048 * HID, HID, 1024);
    tr_k<<<dim3(HID / 64, 1024 / 64), 256, 0, stream>>>(Wv, qkvT + (size_t)3072 * HID, HID, 1024);

    // 1. fused QKV projection: [4096 x 2048] @ [2048 x 4096]
    gemm_bt<<<dim3(M_ROWS / 128, QKV_N / 128), 256, 0, stream>>>(hb, qkvT, qkv, QKV_N, HID);

    // 2. prep (overwrites hb/qkvT — now dead) + k-norm partial maxima
    prep_k<<<dim3(SEQ / 32, NKV, BATCH), 256, 0, stream>>>(qkv, norm_in, pos, sq, qrb, krb, vtb,
                                                           nd, bnd);
    kmax_k<<<dim3(8, NKV, BATCH), 256, 0, stream>>>(qkv, maxp);

    // 3. memory_output -> combined (g * memout / nd)
    memout_k<<<dim3(SEQ / 64, NH, BATCH), 256, 0, stream>>>(sq, mem_in, nd, gate, cb);

    // 4. updated_norm
    normupd_k<<<dim3(NKV, BATCH), 512, 0, stream>>>(qkv, norm_in, out_norm);

    // 5/6. updated_memory
    memupd_k<<<dim3(NSPLIT, NKV, BATCH), 256, 0, stream>>>(qkv, part);
    memred_k<<<(BATCH * NKV * 128 * 128) / 256, 256, 0, stream>>>(part, mem_in, out_mem);

    // 6b. Wo^T (overlays part — dead after memred)
    tr_k<<<dim3(HID / 64, HID / 64), 256, 0, stream>>>(Wo, woT, HID, HID);

    // 7. causal attention (fixed-bound softmax), adds (1-g)*attn into combined
    attn_k<<<dim3(16, NH, BATCH), 256, 0, stream>>>(qrb, krb, vtb, gate, bnd, maxp, cb);

    // 8. output projection: [4096 x 2048] @ [2048 x 2048]
    gemm_bt<<<dim3(M_ROWS / 128, HID / 128), 256, 0, stream>>>(cb, woT, out_final, HID, HID);
}

// Round 6
// 544.892 us; speedup vs baseline: 1.8776x; 1.2324x over previous
//
#include <hip/hip_runtime.h>

// ---------- problem constants ----------
#define BATCH 2
#define SEQ   2048
#define HID   2048
#define NH    16
#define NKV   8
#define HD    128
#define M_ROWS (BATCH * SEQ)          // 4096
#define QKV_N  4096                   // 2048 q | 1024 k | 1024 v

typedef __attribute__((ext_vector_type(8))) __bf16 bf16x8;
typedef __attribute__((ext_vector_type(4))) float  f32x4;

static __device__ __forceinline__ f32x4 mfma16(bf16x8 a, bf16x8 b, f32x4 c) {
    return __builtin_amdgcn_mfma_f32_16x16x32_bf16(a, b, c, 0, 0, 0);
}
static __device__ __forceinline__ float sigma_f(float x) {
    return x > 0.f ? x + 1.f : __expf(x);   // elu(x)+1
}
// async global->LDS, 16B per lane; lds base must be wave-uniform
static __device__ __forceinline__ void gload16(const __bf16* g, __bf16* l) {
    __builtin_amdgcn_global_load_lds(
        (const __attribute__((address_space(1))) void*)g,
        (__attribute__((address_space(3))) void*)l, 16, 0, 0);
}

// ---------- workspace layout (bytes) ----------
#define OFF_QKV  0ull                              // float [4096][4096]   64 MB
#define OFF_SQ   67108864ull                       // bf16  (b,h,S,128)    16 MB  (pre-GEMM: hb)
#define OFF_QR   83886080ull                       // bf16  (b,h,S,128)    16 MB  (pre-GEMM: qkvT)
#define OFF_KR   100663296ull                      // bf16  (b,kvh,S,128)   8 MB
#define OFF_VT   109051904ull                      // bf16  (b,kvh,128,S)   8 MB
#define OFF_ND   117440512ull                      // float (b,h,S)       256 KB
#define OFF_CB   117702656ull                      // bf16  [4096][2048]   16 MB
#define OFF_PART 134479872ull                      // float 8*(b,kvh,128,128) 8 MB (late: woT 8 MB)
#define OFF_BND  142868480ull                      // float (b,h,S)       256 KB  (q row-norm^2)
#define OFF_MAXP 143130624ull                      // float (b,kvh,8)     512 B   (k-norm^2 partial max)
#define OFF_NPART 143131648ull                     // float 8*(b,kvh,128)  64 KB  (sigma_k col-sum partials)
#define NSPLIT 8

// =====================================================================
// K0a: fp32 -> bf16 bulk convert (8 elems/thread)
// =====================================================================
__global__ void f2b_k(const float* __restrict__ src, __bf16* __restrict__ dst)
{
    const size_t i = ((size_t)blockIdx.x * 256 + threadIdx.x) * 8;
    const float4 v0 = *reinterpret_cast<const float4*>(src + i);
    const float4 v1 = *reinterpret_cast<const float4*>(src + i + 4);
    bf16x8 t;
    t[0]=(__bf16)v0.x; t[1]=(__bf16)v0.y; t[2]=(__bf16)v0.z; t[3]=(__bf16)v0.w;
    t[4]=(__bf16)v1.x; t[5]=(__bf16)v1.y; t[6]=(__bf16)v1.z; t[7]=(__bf16)v1.w;
    *reinterpret_cast<bf16x8*>(dst + i) = t;
}

// =====================================================================
// K0b: W fp32 [K][N] -> Bt bf16 [N][K]  (64x64 LDS tile transpose)
// =====================================================================
__global__ __launch_bounds__(256) void tr_k(const float* __restrict__ W,
                                            __bf16* __restrict__ Bt, int K, int N)
{
    __shared__ __bf16 T[64][72];
    const int k0 = blockIdx.x * 64, n0 = blockIdx.y * 64;
    const int t = threadIdx.x;
    #pragma unroll
    for (int i = 0; i < 4; ++i) {
        const int idx = t + i * 256;           // 0..1023
        const int r = idx >> 4, c4 = (idx & 15) * 4;
        const float4 v = *reinterpret_cast<const float4*>(&W[(size_t)(k0 + r) * N + n0 + c4]);
        T[c4 + 0][r] = (__bf16)v.x; T[c4 + 1][r] = (__bf16)v.y;
        T[c4 + 2][r] = (__bf16)v.z; T[c4 + 3][r] = (__bf16)v.w;
    }
    __syncthreads();
    #pragma unroll
    for (int i = 0; i < 2; ++i) {
        const int idx = t + i * 256;           // 0..511
        const int rr = idx >> 3, cc = (idx & 7) * 8;
        *reinterpret_cast<bf16x8*>(&Bt[(size_t)(n0 + rr) * K + k0 + cc]) =
            *reinterpret_cast<bf16x8*>(&T[rr][cc]);
    }
}

// =====================================================================
// K1 / K8: m97-style GEMM. C[M][N] = A[M][K] @ Bt[N][K]^T, fp32 out.
// 128x128 tile, BK=32, global_load_lds width-16 staging.
// =====================================================================
__global__ __launch_bounds__(256) void gemm_bt(const __bf16* __restrict__ A,
                                               const __bf16* __restrict__ Bt,
                                               float* __restrict__ C,
                                               int N, int K)
{
    __shared__ __align__(16) __bf16 As[128 * 32];
    __shared__ __align__(16) __bf16 Bs[128 * 32];

    const int tid = threadIdx.x, wave = tid >> 6, lane = tid & 63;
    const int l15 = lane & 15, l4 = lane >> 4;
    const int m0 = blockIdx.x * 128, n0 = blockIdx.y * 128;
    const int wm = (wave & 1) * 64, wn = (wave >> 1) * 64;

    f32x4 acc[4][4] = {};

    const int srow = wave * 32 + (lane >> 2);
    const int scol = (lane & 3) * 8;
    const __bf16* Ab = A  + (size_t)(m0 + srow) * K + scol;
    const __bf16* Bb = Bt + (size_t)(n0 + srow) * K + scol;
    __bf16* AsB0 = &As[(wave * 32) * 32];
    __bf16* AsB1 = &As[(wave * 32 + 16) * 32];
    __bf16* BsB0 = &Bs[(wave * 32) * 32];
    __bf16* BsB1 = &Bs[(wave * 32 + 16) * 32];

    for (int kb = 0; kb < K; kb += 32) {
        gload16(Ab + kb,            AsB0);
        gload16(Ab + 16 * K + kb,   AsB1);
        gload16(Bb + kb,            BsB0);
        gload16(Bb + 16 * K + kb,   BsB1);
        __syncthreads();

        bf16x8 af[4], bfr[4];
        #pragma unroll
        for (int mt = 0; mt < 4; ++mt)
            af[mt] = *reinterpret_cast<bf16x8*>(&As[(wm + mt * 16 + l15) * 32 + l4 * 8]);
        #pragma unroll
        for (int nt = 0; nt < 4; ++nt)
            bfr[nt] = *reinterpret_cast<bf16x8*>(&Bs[(wn + nt * 16 + l15) * 32 + l4 * 8]);
        #pragma unroll
        for (int mt = 0; mt < 4; ++mt)
            #pragma unroll
            for (int nt = 0; nt < 4; ++nt)
                acc[mt][nt] = mfma16(af[mt], bfr[nt], acc[mt][nt]);
        __syncthreads();
    }

    #pragma unroll
    for (int mt = 0; mt < 4; ++mt)
        #pragma unroll
        for (int nt = 0; nt < 4; ++nt)
            #pragma unroll
            for (int r = 0; r < 4; ++r) {
                const int row = m0 + wm + mt * 16 + l4 * 4 + r;
                const int col = n0 + wn + nt * 16 + l15;
                C[(size_t)row * N + col] = acc[mt][nt][r];
            }
}

// =====================================================================
// K2: prep v2 — grid (SEQ/32, NKV, BATCH), 256 threads.
// Per block: 32 s-rows of one kv-group. Q heads 2kvh,2kvh+1: sigma->sq,
// RoPE*scale->qr, nd=sq.norm dot, bnd=||q||^2*scale^2 (rotation preserves
// norm). K head: RoPE->kr. V head: LDS-transpose -> vt (coalesced).
// No atomics.
// =====================================================================
__global__ __launch_bounds__(256) void prep_k(const float* __restrict__ qkv,
                                              const float* __restrict__ norm_in,
                                              const int* __restrict__ pos_ids,
                                              __bf16* __restrict__ sq, __bf16* __restrict__ qr,
                                              __bf16* __restrict__ kr, __bf16* __restrict__ vt,
                                              float* __restrict__ nd, float* __restrict__ bnd)
{
    const int sc = blockIdx.x, kvh = blockIdx.y, b = blockIdx.z;
    const int s0 = sc * 32, t = threadIdx.x;
    const float scale = 0.08838834764831845f;      // 1/sqrt(128)
    const float s2 = scale * scale;
    const float NEG_LN_TH = -0.14391156831212787f; // -ln(10000)/64

    // ---------- Q phase: 64 rows (2 heads x 32 s), 4 threads/row ----------
    {
        const int row = t >> 2;             // 0..63
        const int head = row >> 5, sl = row & 31;
        const int hq = kvh * 2 + head, nh = hq & 7;
        const int dq = (t & 3) * 16;        // pair-halves [dq,dq+16) & [dq+64,dq+80)
        const int pos = pos_ids[s0 + sl];
        const float* qp = qkv + (size_t)(b * SEQ + s0 + sl) * QKV_N + hq * 128;
        const float* np = norm_in + (b * NKV + nh) * 128;

        float x0[16], x1[16];
        #pragma unroll
        for (int i = 0; i < 16; i += 4) {
            *reinterpret_cast<float4*>(&x0[i]) = *reinterpret_cast<const float4*>(qp + dq + i);
            *reinterpret_cast<float4*>(&x1[i]) = *reinterpret_cast<const float4*>(qp + dq + 64 + i);
        }
        float nds = 0.f, qns = 0.f;
        bf16x8 sqv0[2], sqv1[2], qrv0[2], qrv1[2];
        #pragma unroll
        for (int i = 0; i < 16; ++i) {
            const int j = dq + i;           // 0..63
            float c, sn;
            __sincosf((float)pos * __expf((float)j * NEG_LN_TH), &sn, &c);
            qrv0[i >> 3][i & 7] = (__bf16)((x0[i] * c - x1[i] * sn) * scale);
            qrv1[i >> 3][i & 7] = (__bf16)((x1[i] * c + x0[i] * sn) * scale);
            const float sg0 = sigma_f(x0[i]), sg1 = sigma_f(x1[i]);
            sqv0[i >> 3][i & 7] = (__bf16)sg0;
            sqv1[i >> 3][i & 7] = (__bf16)sg1;
            nds += sg0 * np[j] + sg1 * np[j + 64];
            qns += (x0[i] * x0[i] + x1[i] * x1[i]) * s2;
        }
        __bf16* sqp = sq + ((size_t)(b * NH + hq) * SEQ + s0 + sl) * 128;
        __bf16* qrp = qr + ((size_t)(b * NH + hq) * SEQ + s0 + sl) * 128;
        *reinterpret_cast<bf16x8*>(sqp + dq)      = sqv0[0];
        *reinterpret_cast<bf16x8*>(sqp + dq + 8)  = sqv0[1];
        *reinterpret_cast<bf16x8*>(sqp + dq + 64) = sqv1[0];
        *reinterpret_cast<bf16x8*>(sqp + dq + 72) = sqv1[1];
        *reinterpret_cast<bf16x8*>(qrp + dq)      = qrv0[0];
        *reinterpret_cast<bf16x8*>(qrp + dq + 8)  = qrv0[1];
        *reinterpret_cast<bf16x8*>(qrp + dq + 64) = qrv1[0];
        *reinterpret_cast<bf16x8*>(qrp + dq + 72) = qrv1[1];

        nds += __shfl_xor(nds, 1); nds += __shfl_xor(nds, 2);
        qns += __shfl_xor(qns, 1); qns += __shfl_xor(qns, 2);
        if ((t & 3) == 0) {
            nd [(size_t)(b * NH + hq) * SEQ + s0 + sl] = nds;
            bnd[(size_t)(b * NH + hq) * SEQ + s0 + sl] = qns;
        }
    }

    // ---------- K phase: 32 rows, 4 threads/row (threads 0..127) ----------
    if (t < 128) {
        const int sl = t >> 2;
        const int dq = (t & 3) * 16;
        const int pos = pos_ids[s0 + sl];
        const float* kp = qkv + (size_t)(b * SEQ + s0 + sl) * QKV_N + 2048 + kvh * 128;
        float x0[16], x1[16];
        #pragma unroll
        for (int i = 0; i < 16; i += 4) {
            *reinterpret_cast<float4*>(&x0[i]) = *reinterpret_cast<const float4*>(kp + dq + i);
            *reinterpret_cast<float4*>(&x1[i]) = *reinterpret_cast<const float4*>(kp + dq + 64 + i);
        }
        bf16x8 kv0[2], kv1[2];
        #pragma unroll
        for (int i = 0; i < 16; ++i) {
            const int j = dq + i;
            float c, sn;
            __sincosf((float)pos * __expf((float)j * NEG_LN_TH), &sn, &c);
            kv0[i >> 3][i & 7] = (__bf16)(x0[i] * c - x1[i] * sn);
            kv1[i >> 3][i & 7] = (__bf16)(x1[i] * c + x0[i] * sn);
        }
        __bf16* krp = kr + ((size_t)(b * NKV + kvh) * SEQ + s0 + sl) * 128;
        *reinterpret_cast<bf16x8*>(krp + dq)      = kv0[0];
        *reinterpret_cast<bf16x8*>(krp + dq + 8)  = kv0[1];
        *reinterpret_cast<bf16x8*>(krp + dq + 64) = kv1[0];
        *reinterpret_cast<bf16x8*>(krp + dq + 72) = kv1[1];
    }

    // ---------- V phase: transpose via LDS, coalesced vt writes ----------
    __shared__ float vl[128][33];
    {
        const int sl = t >> 3, dch = (t & 7) * 16;
        const float* vp = qkv + (size_t)(b * SEQ + s0 + sl) * QKV_N + 3072 + kvh * 128 + dch;
        float xv[16];
        #pragma unroll
        for (int i = 0; i < 16; i += 4)
            *reinterpret_cast<float4*>(&xv[i]) = *reinterpret_cast<const float4*>(vp + i);
        #pragma unroll
        for (int i = 0; i < 16; ++i) vl[dch + i][sl] = xv[i];
    }
    __syncthreads();
    {
        const int d = t >> 1, sh = (t & 1) * 16;
        bf16x8 o0, o1;
        #pragma unroll
        for (int j = 0; j < 8; ++j) o0[j] = (__bf16)vl[d][sh + j];
        #pragma unroll
        for (int j = 0; j < 8; ++j) o1[j] = (__bf16)vl[d][sh + 8 + j];
        __bf16* vp = vt + ((size_t)((b * NKV + kvh) * 128 + d)) * SEQ + s0 + sh;
        *reinterpret_cast<bf16x8*>(vp)     = o0;
        *reinterpret_cast<bf16x8*>(vp + 8) = o1;
    }
}

// =====================================================================
// K2b: per-(b,kvh) partial max of ||k_row||^2 over s-chunks of 256.
// RoPE preserves row norms, so raw k suffices. No atomics.
// =====================================================================
__global__ __launch_bounds__(256) void kmax_k(const float* __restrict__ qkv,
                                              float* __restrict__ maxp)
{
    const int sc = blockIdx.x, kvh = blockIdx.y, b = blockIdx.z;
    const int t = threadIdx.x;
    const int s = sc * 256 + t;
    const float* kp = qkv + (size_t)(b * SEQ + s) * QKV_N + 2048 + kvh * 128;
    float sum = 0.f;
    #pragma unroll
    for (int i = 0; i < 128; i += 4) {
        const float4 v = *reinterpret_cast<const float4*>(kp + i);
        sum += v.x * v.x + v.y * v.y + v.z * v.z + v.w * v.w;
    }
    #pragma unroll
    for (int off = 32; off > 0; off >>= 1) sum = fmaxf(sum, __shfl_xor(sum, off));
    __shared__ float wm[4];
    if ((t & 63) == 0) wm[t >> 6] = sum;
    __syncthreads();
    if (t == 0)
        maxp[(b * NKV + kvh) * 8 + sc] = fmaxf(fmaxf(wm[0], wm[1]), fmaxf(wm[2], wm[3]));
}

// =====================================================================
// K3: memory_output = (sigma_q @ mem) / nd, write g*val into combined
// =====================================================================
__global__ __launch_bounds__(256) void memout_k(const __bf16* __restrict__ sq,
                                                const float* __restrict__ mem_in,
                                                const float* __restrict__ nd,
                                                const float* __restrict__ gate,
                                                __bf16* __restrict__ cb)
{
    __shared__ __align__(16) __bf16 mt[128][136];   // mem^T [e][d]
    const int tid = threadIdx.x;
    const int h = blockIdx.y, b = blockIdx.z;
    const int s0 = blockIdx.x * 64;

    const float* mem = mem_in + (size_t)(b * NKV + (h & 7)) * 16384;
    for (int i = tid; i < 16384; i += 256) {
        int dd = i >> 7, e = i & 127;
        mt[e][dd] = (__bf16)mem[i];
    }
    __syncthreads();

    const int wave = tid >> 6, lane = tid & 63, l15 = lane & 15, l4 = lane >> 4;
    f32x4 acc[8] = {};
    const __bf16* sqb = sq + ((size_t)(b * NH + h) * SEQ + s0 + wave * 16 + l15) * 128;
    #pragma unroll
    for (int kb = 0; kb < 4; ++kb) {
        bf16x8 a = *reinterpret_cast<const bf16x8*>(sqb + kb * 32 + l4 * 8);
        #pragma unroll
        for (int nc = 0; nc < 8; ++nc) {
            bf16x8 bb = *reinterpret_cast<bf16x8*>(&mt[nc * 16 + l15][kb * 32 + l4 * 8]);
            acc[nc] = mfma16(a, bb, acc[nc]);
        }
    }
    float g = 1.f / (1.f + __expf(-gate[h]));
    #pragma unroll
    for (int r = 0; r < 4; ++r) {
        int srow = s0 + wave * 16 + l4 * 4 + r;
        float scl = g / nd[(size_t)(b * NH + h) * SEQ + srow];
        __bf16* cbp = cb + (size_t)(b * SEQ + srow) * HID + h * 128;
        #pragma unroll
        for (int nc = 0; nc < 8; ++nc)
            cbp[nc * 16 + l15] = (__bf16)(acc[nc][r] * scl);
    }
}

// =====================================================================
// K5: updated_memory partials + sigma_k column-sum partials.
// part[sp] = sigma_k^T @ v over s-chunk; npart[sp] = sum_s sigma_k.
// =====================================================================
__global__ __launch_bounds__(256) void memupd_k(const float* __restrict__ qkv,
                                                float* __restrict__ part,
                                                float* __restrict__ npart)
{
    const int sp = blockIdx.x, h = blockIdx.y, b = blockIdx.z;
    const int tid = threadIdx.x;
    const int tx = tid & 15, ty = tid >> 4;   // d-block tx*8, e-block ty*8
    __shared__ __align__(16) float sk[8][128];
    __shared__ __align__(16) float sv[8][128];
    float acc[8][8] = {};
    float nacc = 0.f;                          // threads 0..127: sum_s sigma_k[.,tid]

    const int s0 = sp * (SEQ / NSPLIT);
    for (int so = 0; so < SEQ / NSPLIT; so += 8) {
        for (int i = tid; i < 8 * 128; i += 256) {
            int rr = i >> 7, dd = i & 127;
            const float* rowp = qkv + (size_t)(b * SEQ + s0 + so + rr) * QKV_N;
            sk[rr][dd] = sigma_f(rowp[2048 + h * 128 + dd]);
            sv[rr][dd] = rowp[3072 + h * 128 + dd];
        }
        __syncthreads();
        if (tid < 128) {
            #pragma unroll
            for (int rr = 0; rr < 8; ++rr) nacc += sk[rr][tid];
        }
        #pragma unroll
        for (int rr = 0; rr < 8; ++rr) {
            float4 k0 = *reinterpret_cast<float4*>(&sk[rr][tx * 8]);
            float4 k1 = *reinterpret_cast<float4*>(&sk[rr][tx * 8 + 4]);
            float4 v0 = *reinterpret_cast<float4*>(&sv[rr][ty * 8]);
            float4 v1 = *reinterpret_cast<float4*>(&sv[rr][ty * 8 + 4]);
            float kreg[8] = {k0.x,k0.y,k0.z,k0.w,k1.x,k1.y,k1.z,k1.w};
            float vreg[8] = {v0.x,v0.y,v0.z,v0.w,v1.x,v1.y,v1.z,v1.w};
            #pragma unroll
            for (int i = 0; i < 8; ++i)
                #pragma unroll
                for (int j2 = 0; j2 < 8; ++j2)
                    acc[i][j2] += kreg[i] * vreg[j2];
        }
        __syncthreads();
    }
    float* pb = part + ((size_t)sp * (BATCH * NKV) + b * NKV + h) * 16384;
    #pragma unroll
    for (int i = 0; i < 8; ++i)
        #pragma unroll
        for (int j2 = 0; j2 < 8; ++j2)
            pb[(tx * 8 + i) * 128 + ty * 8 + j2] = acc[i][j2];
    if (tid < 128)
        npart[((size_t)sp * (BATCH * NKV) + b * NKV + h) * 128 + tid] = nacc;
}

// K6: reduce partials + memory_in
__global__ void memred_k(const float* __restrict__ part, const float* __restrict__ mem_in,
                         float* __restrict__ out_mem)
{
    const size_t i = (size_t)blockIdx.x * 256 + threadIdx.x;   // 262144 total
    float a = mem_in[i];
    #pragma unroll
    for (int sp = 0; sp < NSPLIT; ++sp) a += part[(size_t)sp * 262144 + i];
    out_mem[i] = a;
}

// K6b: updated_norm = norm_in + sum_sp npart
__global__ void normred_k(const float* __restrict__ npart, const float* __restrict__ norm_in,
                          float* __restrict__ out_norm)
{
    const int bh = blockIdx.x, d = threadIdx.x;    // 16 blocks x 128 threads
    float a = norm_in[bh * 128 + d];
    #pragma unroll
    for (int sp = 0; sp < NSPLIT; ++sp)
        a += npart[((size_t)sp * (BATCH * NKV) + bh) * 128 + d];
    out_norm[bh * 128 + d] = a;
}

// =====================================================================
// K7: flash causal attention — fixed-bound softmax (no shuffles, no
// rescale): m = ||q||*max||k||+1 >= any score (Cauchy-Schwarz, RoPE is a
// rotation). li accumulated via MFMA against a ones B-fragment.
// Balanced q-tile pairs; K/V staged in LDS.
// =====================================================================
__global__ __launch_bounds__(256) void attn_k(const __bf16* __restrict__ qr,
                                              const __bf16* __restrict__ kr,
                                              const __bf16* __restrict__ vt,
                                              const float* __restrict__ gate,
                                              const float* __restrict__ bnd,
                                              const float* __restrict__ maxp,
                                              __bf16* __restrict__ cb)
{
    __shared__ __align__(16) __bf16 Ks[64][136];    // [key][d]   (+8 pad)
    __shared__ __align__(16) __bf16 Vs[128][72];    // [d][key]   (+8 pad)
    __shared__ __align__(16) __bf16 plds[4][16][72];// per-wave P transpose

    const int tid = threadIdx.x, wave = tid >> 6, lane = tid & 63;
    const int l15 = lane & 15, l4 = lane >> 4;
    const int h = blockIdx.y, b = blockIdx.z;
    const int kvh = h >> 1;

    const __bf16* kbase = kr + (size_t)(b * NKV + kvh) * SEQ * 128;
    const __bf16* vbase = vt + (size_t)(b * NKV + kvh) * 128 * SEQ;
    const float* bbase  = bnd + (size_t)(b * NH + h) * SEQ;

    const float g  = 1.f / (1.f + __expf(-gate[h]));
    const float gi = 1.f - g;
    float kn2 = 0.f;
    const float* mp = maxp + (b * NKV + kvh) * 8;
    #pragma unroll
    for (int i = 0; i < 8; ++i) kn2 = fmaxf(kn2, mp[i]);
    const float knmax = sqrtf(kn2);

    bf16x8 ones;
    #pragma unroll
    for (int j = 0; j < 8; ++j) ones[j] = (__bf16)1.0f;

    const int k_row = tid >> 4, k_col = (tid & 15) * 8;   // K: 16 rows/round
    const int v_row = tid >> 3, v_col = (tid & 7) * 8;    // V: 32 rows/round

    #pragma unroll 1
    for (int tile = 0; tile < 2; ++tile) {
        const int q0 = (tile == 0 ? blockIdx.x : 31 - blockIdx.x) * 64;
        const int qw = q0 + wave * 16;

        const __bf16* qbase = qr + ((size_t)(b * NH + h) * SEQ + qw + l15) * 128;
        bf16x8 af[4];
        #pragma unroll
        for (int kb = 0; kb < 4; ++kb)
            af[kb] = *reinterpret_cast<const bf16x8*>(qbase + kb * 32 + l4 * 8);

        // fixed safe bound per q-row
        float m_r[4];
        #pragma unroll
        for (int r = 0; r < 4; ++r)
            m_r[r] = sqrtf(bbase[qw + l4 * 4 + r]) * knmax + 1.0f;

        f32x4 o[8] = {};
        f32x4 lacc = {};

        #pragma unroll 1
        for (int kt = 0; kt < q0 + 64; kt += 64) {
            // ---- cooperative staging of K (64x128) and V^T (128x64) ----
            #pragma unroll
            for (int r = 0; r < 4; ++r) {
                *reinterpret_cast<bf16x8*>(&Ks[r * 16 + k_row][k_col]) =
                    *reinterpret_cast<const bf16x8*>(kbase + (size_t)(kt + r * 16 + k_row) * 128 + k_col);
            }
            #pragma unroll
            for (int r = 0; r < 4; ++r) {
                *reinterpret_cast<bf16x8*>(&Vs[r * 32 + v_row][v_col]) =
                    *reinterpret_cast<const bf16x8*>(vbase + (size_t)(r * 32 + v_row) * SEQ + kt + v_col);
            }
            __syncthreads();

            // ---- QK^T ----
            f32x4 sv[4] = {};
            #pragma unroll
            for (int kb = 0; kb < 4; ++kb) {
                #pragma unroll
                for (int sub = 0; sub < 4; ++sub) {
                    bf16x8 bb = *reinterpret_cast<bf16x8*>(&Ks[sub * 16 + l15][kb * 32 + l4 * 8]);
                    sv[sub] = mfma16(af[kb], bb, sv[sub]);
                }
            }

            // ---- exp with fixed bound, causal mask, store P ----
            #pragma unroll
            for (int r = 0; r < 4; ++r) {
                const int qrow = qw + l4 * 4 + r;
                #pragma unroll
                for (int sub = 0; sub < 4; ++sub) {
                    const int key = kt + sub * 16 + l15;
                    float p = __expf(sv[sub][r] - m_r[r]);
                    p = (key <= qrow) ? p : 0.f;
                    plds[wave][l4 * 4 + r][sub * 16 + l15] = (__bf16)p;
                }
            }

            // ---- PV + row-sum via ones-fragment ----
            bf16x8 ap0 = *reinterpret_cast<bf16x8*>(&plds[wave][l15][l4 * 8]);
            bf16x8 ap1 = *reinterpret_cast<bf16x8*>(&plds[wave][l15][32 + l4 * 8]);
            lacc = mfma16(ap0, ones, lacc);
            lacc = mfma16(ap1, ones, lacc);
            #pragma unroll
            for (int nc = 0; nc < 8; ++nc) {
                bf16x8 b0 = *reinterpret_cast<bf16x8*>(&Vs[nc * 16 + l15][l4 * 8]);
                bf16x8 b1 = *reinterpret_cast<bf16x8*>(&Vs[nc * 16 + l15][32 + l4 * 8]);
                o[nc] = mfma16(ap0, b0, o[nc]);
                o[nc] = mfma16(ap1, b1, o[nc]);
            }
            __syncthreads();
        }

        // ---- epilogue: add (1-g) * attn / li into combined ----
        #pragma unroll
        for (int r = 0; r < 4; ++r) {
            const int qrow = qw + l4 * 4 + r;
            const float inv = gi / lacc[r];
            __bf16* cbp = cb + (size_t)(b * SEQ + qrow) * HID + h * 128;
            #pragma unroll
            for (int nc = 0; nc < 8; ++nc) {
                const int dd = nc * 16 + l15;
                float prev = (float)cbp[dd];
                cbp[dd] = (__bf16)(prev + o[nc][r] * inv);
            }
        }
    }
}

// =====================================================================
extern "C" void kernel_launch(void* const* d_in, const int* in_sizes, int n_in,
                              void* d_out, int out_size, void* d_ws, size_t ws_size,
                              hipStream_t stream)
{
    const float* hidden  = (const float*)d_in[0];
    const float* Wq      = (const float*)d_in[1];
    const float* Wk      = (const float*)d_in[2];
    const float* Wv      = (const float*)d_in[3];
    const float* Wo      = (const float*)d_in[4];
    const float* gate    = (const float*)d_in[5];
    const float* mem_in  = (const float*)d_in[6];
    const float* norm_in = (const float*)d_in[7];
    const int*   pos     = (const int*)d_in[8];

    float* out_final = (float*)d_out;                  // (B,S,HID)
    float* out_mem   = out_final + (size_t)BATCH * SEQ * HID;     // (B,8,128,128)
    float* out_norm  = out_mem + (size_t)BATCH * NKV * 128 * 128; // (B,8,1,128)

    char* ws = (char*)d_ws;
    float*  qkv  = (float*)(ws + OFF_QKV);
    __bf16* sq   = (__bf16*)(ws + OFF_SQ);
    __bf16* qrb  = (__bf16*)(ws + OFF_QR);
    __bf16* krb  = (__bf16*)(ws + OFF_KR);
    __bf16* vtb  = (__bf16*)(ws + OFF_VT);
    float*  nd   = (float*)(ws + OFF_ND);
    __bf16* cb   = (__bf16*)(ws + OFF_CB);
    float*  part = (float*)(ws + OFF_PART);
    float*  bnd  = (float*)(ws + OFF_BND);
    float*  maxp = (float*)(ws + OFF_MAXP);
    float*  npart = (float*)(ws + OFF_NPART);
    // overlays (lifetimes disjoint from the named owners):
    __bf16* hb   = (__bf16*)(ws + OFF_SQ);    // bf16 hidden  [4096][2048], dead after gemm1
    __bf16* qkvT = (__bf16*)(ws + OFF_QR);    // bf16 W_qkv^T [4096][2048], dead after gemm1
    __bf16* woT  = (__bf16*)(ws + OFF_PART);  // bf16 Wo^T    [2048][2048], after memred

    // 0. bf16 conversions / weight transposes
    f2b_k<<<(M_ROWS * HID) / (256 * 8), 256, 0, stream>>>(hidden, hb);
    tr_k<<<dim3(HID / 64, 2048 / 64), 256, 0, stream>>>(Wq, qkvT, HID, 2048);
    tr_k<<<dim3(HID / 64, 1024 / 64), 256, 0, stream>>>(Wk, qkvT + (size_t)2048 * HID, HID, 1024);
    tr_k<<<dim3(HID / 64, 1024 / 64), 256, 0, stream>>>(Wv, qkvT + (size_t)3072 * HID, HID, 1024);

    // 1. fused QKV projection: [4096 x 2048] @ [2048 x 4096]
    gemm_bt<<<dim3(M_ROWS / 128, QKV_N / 128), 256, 0, stream>>>(hb, qkvT, qkv, QKV_N, HID);

    // 2. prep (overwrites hb/qkvT — now dead) + k-norm partial maxima
    prep_k<<<dim3(SEQ / 32, NKV, BATCH), 256, 0, stream>>>(qkv, norm_in, pos, sq, qrb, krb, vtb,
                                                           nd, bnd);
    kmax_k<<<dim3(8, NKV, BATCH), 256, 0, stream>>>(qkv, maxp);

    // 3. memory_output -> combined (g * memout / nd)
    memout_k<<<dim3(SEQ / 64, NH, BATCH), 256, 0, stream>>>(sq, mem_in, nd, gate, cb);

    // 4/5. updated_memory (+ sigma_k col-sum partials)
    memupd_k<<<dim3(NSPLIT, NKV, BATCH), 256, 0, stream>>>(qkv, part, npart);
    memred_k<<<(BATCH * NKV * 128 * 128) / 256, 256, 0, stream>>>(part, mem_in, out_mem);
    normred_k<<<BATCH * NKV, 128, 0, stream>>>(npart, norm_in, out_norm);

    // 6b. Wo^T (overlays part — dead after memred)
    tr_k<<<dim3(HID / 64, HID / 64), 256, 0, stream>>>(Wo, woT, HID, HID);

    // 7. causal attention (fixed-bound softmax), adds (1-g)*attn into combined
    attn_k<<<dim3(16, NH, BATCH), 256, 0, stream>>>(qrb, krb, vtb, gate, bnd, maxp, cb);

    // 8. output projection: [4096 x 2048] @ [2048 x 2048]
    gemm_bt<<<dim3(M_ROWS / 128, HID / 128), 256, 0, stream>>>(cb, woT, out_final, HID, HID);
}

// Round 7
// 506.141 us; speedup vs baseline: 2.0214x; 1.0766x over previous
//
#include <hip/hip_runtime.h>

// ---------- problem constants ----------
#define BATCH 2
#define SEQ   2048
#define HID   2048
#define NH    16
#define NKV   8
#define HD    128
#define M_ROWS (BATCH * SEQ)          // 4096
#define QKV_N  4096                   // 2048 q | 1024 k | 1024 v

typedef __attribute__((ext_vector_type(8))) __bf16 bf16x8;
typedef __attribute__((ext_vector_type(4))) float  f32x4;

static __device__ __forceinline__ f32x4 mfma16(bf16x8 a, bf16x8 b, f32x4 c) {
    return __builtin_amdgcn_mfma_f32_16x16x32_bf16(a, b, c, 0, 0, 0);
}
static __device__ __forceinline__ float sigma_f(float x) {
    return x > 0.f ? x + 1.f : __expf(x);   // elu(x)+1
}
// async global->LDS, 16B per lane; lds base must be wave-uniform
static __device__ __forceinline__ void gload16(const __bf16* g, __bf16* l) {
    __builtin_amdgcn_global_load_lds(
        (const __attribute__((address_space(1))) void*)g,
        (__attribute__((address_space(3))) void*)l, 16, 0, 0);
}

// ---------- workspace layout (bytes) ----------
#define OFF_QKV  0ull                              // float [4096][4096]   64 MB
#define OFF_SQ   67108864ull                       // bf16  (b,h,S,128)    16 MB  (pre-GEMM: hb)
#define OFF_QR   83886080ull                       // bf16  (b,h,S,128)    16 MB  (pre-GEMM: qkvT)
#define OFF_KR   100663296ull                      // bf16  (b,kvh,S,128)   8 MB
#define OFF_VT   109051904ull                      // bf16  (b,kvh,128,S)   8 MB
#define OFF_ND   117440512ull                      // float (b,h,S)       256 KB
#define OFF_CB   117702656ull                      // bf16  [4096][2048]   16 MB
#define OFF_PART 134479872ull                      // float 8*(b,kvh,128,128) 8 MB (late: woT 8 MB)
#define OFF_BND  142868480ull                      // float (b,h,S)       256 KB  (q row-norm^2)
#define OFF_MAXP 143130624ull                      // float (b,kvh,64)     4 KB   (k-norm^2 chunk max)
#define OFF_NPART 143134720ull                     // float 8*(b,kvh,128)  64 KB  (sigma_k col-sum partials)
#define NSPLIT 8

// =====================================================================
// K0a: fp32 -> bf16 bulk convert (8 elems/thread)
// =====================================================================
__global__ void f2b_k(const float* __restrict__ src, __bf16* __restrict__ dst)
{
    const size_t i = ((size_t)blockIdx.x * 256 + threadIdx.x) * 8;
    const float4 v0 = *reinterpret_cast<const float4*>(src + i);
    const float4 v1 = *reinterpret_cast<const float4*>(src + i + 4);
    bf16x8 t;
    t[0]=(__bf16)v0.x; t[1]=(__bf16)v0.y; t[2]=(__bf16)v0.z; t[3]=(__bf16)v0.w;
    t[4]=(__bf16)v1.x; t[5]=(__bf16)v1.y; t[6]=(__bf16)v1.z; t[7]=(__bf16)v1.w;
    *reinterpret_cast<bf16x8*>(dst + i) = t;
}

// =====================================================================
// K0b: W fp32 [K][N] -> Bt bf16 [N][K]  (64x64 LDS tile transpose)
// =====================================================================
__global__ __launch_bounds__(256) void tr_k(const float* __restrict__ W,
                                            __bf16* __restrict__ Bt, int K, int N)
{
    __shared__ __bf16 T[64][72];
    const int k0 = blockIdx.x * 64, n0 = blockIdx.y * 64;
    const int t = threadIdx.x;
    #pragma unroll
    for (int i = 0; i < 4; ++i) {
        const int idx = t + i * 256;           // 0..1023
        const int r = idx >> 4, c4 = (idx & 15) * 4;
        const float4 v = *reinterpret_cast<const float4*>(&W[(size_t)(k0 + r) * N + n0 + c4]);
        T[c4 + 0][r] = (__bf16)v.x; T[c4 + 1][r] = (__bf16)v.y;
        T[c4 + 2][r] = (__bf16)v.z; T[c4 + 3][r] = (__bf16)v.w;
    }
    __syncthreads();
    #pragma unroll
    for (int i = 0; i < 2; ++i) {
        const int idx = t + i * 256;           // 0..511
        const int rr = idx >> 3, cc = (idx & 7) * 8;
        *reinterpret_cast<bf16x8*>(&Bt[(size_t)(n0 + rr) * K + k0 + cc]) =
            *reinterpret_cast<bf16x8*>(&T[rr][cc]);
    }
}

// =====================================================================
// K1 / K8: m97-style GEMM. C[M][N] = A[M][K] @ Bt[N][K]^T, fp32 out.
// 128x128 tile, BK=32, global_load_lds width-16 staging.
// =====================================================================
__global__ __launch_bounds__(256) void gemm_bt(const __bf16* __restrict__ A,
                                               const __bf16* __restrict__ Bt,
                                               float* __restrict__ C,
                                               int N, int K)
{
    __shared__ __align__(16) __bf16 As[128 * 32];
    __shared__ __align__(16) __bf16 Bs[128 * 32];

    const int tid = threadIdx.x, wave = tid >> 6, lane = tid & 63;
    const int l15 = lane & 15, l4 = lane >> 4;
    const int m0 = blockIdx.x * 128, n0 = blockIdx.y * 128;
    const int wm = (wave & 1) * 64, wn = (wave >> 1) * 64;

    f32x4 acc[4][4] = {};

    const int srow = wave * 32 + (lane >> 2);
    const int scol = (lane & 3) * 8;
    const __bf16* Ab = A  + (size_t)(m0 + srow) * K + scol;
    const __bf16* Bb = Bt + (size_t)(n0 + srow) * K + scol;
    __bf16* AsB0 = &As[(wave * 32) * 32];
    __bf16* AsB1 = &As[(wave * 32 + 16) * 32];
    __bf16* BsB0 = &Bs[(wave * 32) * 32];
    __bf16* BsB1 = &Bs[(wave * 32 + 16) * 32];

    for (int kb = 0; kb < K; kb += 32) {
        gload16(Ab + kb,            AsB0);
        gload16(Ab + 16 * K + kb,   AsB1);
        gload16(Bb + kb,            BsB0);
        gload16(Bb + 16 * K + kb,   BsB1);
        __syncthreads();

        bf16x8 af[4], bfr[4];
        #pragma unroll
        for (int mt = 0; mt < 4; ++mt)
            af[mt] = *reinterpret_cast<bf16x8*>(&As[(wm + mt * 16 + l15) * 32 + l4 * 8]);
        #pragma unroll
        for (int nt = 0; nt < 4; ++nt)
            bfr[nt] = *reinterpret_cast<bf16x8*>(&Bs[(wn + nt * 16 + l15) * 32 + l4 * 8]);
        #pragma unroll
        for (int mt = 0; mt < 4; ++mt)
            #pragma unroll
            for (int nt = 0; nt < 4; ++nt)
                acc[mt][nt] = mfma16(af[mt], bfr[nt], acc[mt][nt]);
        __syncthreads();
    }

    #pragma unroll
    for (int mt = 0; mt < 4; ++mt)
        #pragma unroll
        for (int nt = 0; nt < 4; ++nt)
            #pragma unroll
            for (int r = 0; r < 4; ++r) {
                const int row = m0 + wm + mt * 16 + l4 * 4 + r;
                const int col = n0 + wn + nt * 16 + l15;
                C[(size_t)row * N + col] = acc[mt][nt][r];
            }
}

// =====================================================================
// K2: prep v3 — grid (SEQ/32, NKV, BATCH), 256 threads.
// Adds per-chunk max ||k_row||^2 -> maxp (replaces kmax_k; k already
// loaded here, RoPE preserves norms). No atomics.
// =====================================================================
__global__ __launch_bounds__(256) void prep_k(const float* __restrict__ qkv,
                                              const float* __restrict__ norm_in,
                                              const int* __restrict__ pos_ids,
                                              __bf16* __restrict__ sq, __bf16* __restrict__ qr,
                                              __bf16* __restrict__ kr, __bf16* __restrict__ vt,
                                              float* __restrict__ nd, float* __restrict__ bnd,
                                              float* __restrict__ maxp)
{
    const int sc = blockIdx.x, kvh = blockIdx.y, b = blockIdx.z;
    const int s0 = sc * 32, t = threadIdx.x;
    const float scale = 0.08838834764831845f;      // 1/sqrt(128)
    const float s2 = scale * scale;
    const float NEG_LN_TH = -0.14391156831212787f; // -ln(10000)/64
    __shared__ float krn[32];

    // ---------- Q phase: 64 rows (2 heads x 32 s), 4 threads/row ----------
    {
        const int row = t >> 2;             // 0..63
        const int head = row >> 5, sl = row & 31;
        const int hq = kvh * 2 + head, nh = hq & 7;
        const int dq = (t & 3) * 16;        // pair-halves [dq,dq+16) & [dq+64,dq+80)
        const int pos = pos_ids[s0 + sl];
        const float* qp = qkv + (size_t)(b * SEQ + s0 + sl) * QKV_N + hq * 128;
        const float* np = norm_in + (b * NKV + nh) * 128;

        float x0[16], x1[16];
        #pragma unroll
        for (int i = 0; i < 16; i += 4) {
            *reinterpret_cast<float4*>(&x0[i]) = *reinterpret_cast<const float4*>(qp + dq + i);
            *reinterpret_cast<float4*>(&x1[i]) = *reinterpret_cast<const float4*>(qp + dq + 64 + i);
        }
        float nds = 0.f, qns = 0.f;
        bf16x8 sqv0[2], sqv1[2], qrv0[2], qrv1[2];
        #pragma unroll
        for (int i = 0; i < 16; ++i) {
            const int j = dq + i;           // 0..63
            float c, sn;
            __sincosf((float)pos * __expf((float)j * NEG_LN_TH), &sn, &c);
            qrv0[i >> 3][i & 7] = (__bf16)((x0[i] * c - x1[i] * sn) * scale);
            qrv1[i >> 3][i & 7] = (__bf16)((x1[i] * c + x0[i] * sn) * scale);
            const float sg0 = sigma_f(x0[i]), sg1 = sigma_f(x1[i]);
            sqv0[i >> 3][i & 7] = (__bf16)sg0;
            sqv1[i >> 3][i & 7] = (__bf16)sg1;
            nds += sg0 * np[j] + sg1 * np[j + 64];
            qns += (x0[i] * x0[i] + x1[i] * x1[i]) * s2;
        }
        __bf16* sqp = sq + ((size_t)(b * NH + hq) * SEQ + s0 + sl) * 128;
        __bf16* qrp = qr + ((size_t)(b * NH + hq) * SEQ + s0 + sl) * 128;
        *reinterpret_cast<bf16x8*>(sqp + dq)      = sqv0[0];
        *reinterpret_cast<bf16x8*>(sqp + dq + 8)  = sqv0[1];
        *reinterpret_cast<bf16x8*>(sqp + dq + 64) = sqv1[0];
        *reinterpret_cast<bf16x8*>(sqp + dq + 72) = sqv1[1];
        *reinterpret_cast<bf16x8*>(qrp + dq)      = qrv0[0];
        *reinterpret_cast<bf16x8*>(qrp + dq + 8)  = qrv0[1];
        *reinterpret_cast<bf16x8*>(qrp + dq + 64) = qrv1[0];
        *reinterpret_cast<bf16x8*>(qrp + dq + 72) = qrv1[1];

        nds += __shfl_xor(nds, 1); nds += __shfl_xor(nds, 2);
        qns += __shfl_xor(qns, 1); qns += __shfl_xor(qns, 2);
        if ((t & 3) == 0) {
            nd [(size_t)(b * NH + hq) * SEQ + s0 + sl] = nds;
            bnd[(size_t)(b * NH + hq) * SEQ + s0 + sl] = qns;
        }
    }

    // ---------- K phase: 32 rows, 4 threads/row (threads 0..127) ----------
    if (t < 128) {
        const int sl = t >> 2;
        const int dq = (t & 3) * 16;
        const int pos = pos_ids[s0 + sl];
        const float* kp = qkv + (size_t)(b * SEQ + s0 + sl) * QKV_N + 2048 + kvh * 128;
        float x0[16], x1[16];
        #pragma unroll
        for (int i = 0; i < 16; i += 4) {
            *reinterpret_cast<float4*>(&x0[i]) = *reinterpret_cast<const float4*>(kp + dq + i);
            *reinterpret_cast<float4*>(&x1[i]) = *reinterpret_cast<const float4*>(kp + dq + 64 + i);
        }
        bf16x8 kv0[2], kv1[2];
        float kns = 0.f;
        #pragma unroll
        for (int i = 0; i < 16; ++i) {
            const int j = dq + i;
            float c, sn;
            __sincosf((float)pos * __expf((float)j * NEG_LN_TH), &sn, &c);
            kv0[i >> 3][i & 7] = (__bf16)(x0[i] * c - x1[i] * sn);
            kv1[i >> 3][i & 7] = (__bf16)(x1[i] * c + x0[i] * sn);
            kns += x0[i] * x0[i] + x1[i] * x1[i];
        }
        __bf16* krp = kr + ((size_t)(b * NKV + kvh) * SEQ + s0 + sl) * 128;
        *reinterpret_cast<bf16x8*>(krp + dq)      = kv0[0];
        *reinterpret_cast<bf16x8*>(krp + dq + 8)  = kv0[1];
        *reinterpret_cast<bf16x8*>(krp + dq + 64) = kv1[0];
        *reinterpret_cast<bf16x8*>(krp + dq + 72) = kv1[1];
        kns += __shfl_xor(kns, 1); kns += __shfl_xor(kns, 2);
        if ((t & 3) == 0) krn[sl] = kns;
    }

    // ---------- V phase: transpose via LDS, coalesced vt writes ----------
    __shared__ float vl[128][33];
    {
        const int sl = t >> 3, dch = (t & 7) * 16;
        const float* vp = qkv + (size_t)(b * SEQ + s0 + sl) * QKV_N + 3072 + kvh * 128 + dch;
        float xv[16];
        #pragma unroll
        for (int i = 0; i < 16; i += 4)
            *reinterpret_cast<float4*>(&xv[i]) = *reinterpret_cast<const float4*>(vp + i);
        #pragma unroll
        for (int i = 0; i < 16; ++i) vl[dch + i][sl] = xv[i];
    }
    __syncthreads();
    if (t == 0) {
        float mx = 0.f;
        #pragma unroll
        for (int i = 0; i < 32; ++i) mx = fmaxf(mx, krn[i]);
        maxp[((b * NKV + kvh) << 6) + sc] = mx;
    }
    {
        const int d = t >> 1, sh = (t & 1) * 16;
        bf16x8 o0, o1;
        #pragma unroll
        for (int j = 0; j < 8; ++j) o0[j] = (__bf16)vl[d][sh + j];
        #pragma unroll
        for (int j = 0; j < 8; ++j) o1[j] = (__bf16)vl[d][sh + 8 + j];
        __bf16* vp = vt + ((size_t)((b * NKV + kvh) * 128 + d)) * SEQ + s0 + sh;
        *reinterpret_cast<bf16x8*>(vp)     = o0;
        *reinterpret_cast<bf16x8*>(vp + 8) = o1;
    }
}

// =====================================================================
// K3: memory_output = (sigma_q @ mem) / nd, write g*val into combined
// =====================================================================
__global__ __launch_bounds__(256) void memout_k(const __bf16* __restrict__ sq,
                                                const float* __restrict__ mem_in,
                                                const float* __restrict__ nd,
                                                const float* __restrict__ gate,
                                                __bf16* __restrict__ cb)
{
    __shared__ __align__(16) __bf16 mt[128][136];   // mem^T [e][d]
    const int tid = threadIdx.x;
    const int h = blockIdx.y, b = blockIdx.z;
    const int s0 = blockIdx.x * 64;

    const float* mem = mem_in + (size_t)(b * NKV + (h & 7)) * 16384;
    for (int i = tid; i < 16384; i += 256) {
        int dd = i >> 7, e = i & 127;
        mt[e][dd] = (__bf16)mem[i];
    }
    __syncthreads();

    const int wave = tid >> 6, lane = tid & 63, l15 = lane & 15, l4 = lane >> 4;
    f32x4 acc[8] = {};
    const __bf16* sqb = sq + ((size_t)(b * NH + h) * SEQ + s0 + wave * 16 + l15) * 128;
    #pragma unroll
    for (int kb = 0; kb < 4; ++kb) {
        bf16x8 a = *reinterpret_cast<const bf16x8*>(sqb + kb * 32 + l4 * 8);
        #pragma unroll
        for (int nc = 0; nc < 8; ++nc) {
            bf16x8 bb = *reinterpret_cast<bf16x8*>(&mt[nc * 16 + l15][kb * 32 + l4 * 8]);
            acc[nc] = mfma16(a, bb, acc[nc]);
        }
    }
    float g = 1.f / (1.f + __expf(-gate[h]));
    #pragma unroll
    for (int r = 0; r < 4; ++r) {
        int srow = s0 + wave * 16 + l4 * 4 + r;
        float scl = g / nd[(size_t)(b * NH + h) * SEQ + srow];
        __bf16* cbp = cb + (size_t)(b * SEQ + srow) * HID + h * 128;
        #pragma unroll
        for (int nc = 0; nc < 8; ++nc)
            cbp[nc * 16 + l15] = (__bf16)(acc[nc][r] * scl);
    }
}

// =====================================================================
// K5: updated_memory partials + sigma_k column-sum partials.
// =====================================================================
__global__ __launch_bounds__(256) void memupd_k(const float* __restrict__ qkv,
                                                float* __restrict__ part,
                                                float* __restrict__ npart)
{
    const int sp = blockIdx.x, h = blockIdx.y, b = blockIdx.z;
    const int tid = threadIdx.x;
    const int tx = tid & 15, ty = tid >> 4;   // d-block tx*8, e-block ty*8
    __shared__ __align__(16) float sk[8][128];
    __shared__ __align__(16) float sv[8][128];
    float acc[8][8] = {};
    float nacc = 0.f;                          // threads 0..127: sum_s sigma_k[.,tid]

    const int s0 = sp * (SEQ / NSPLIT);
    for (int so = 0; so < SEQ / NSPLIT; so += 8) {
        for (int i = tid; i < 8 * 128; i += 256) {
            int rr = i >> 7, dd = i & 127;
            const float* rowp = qkv + (size_t)(b * SEQ + s0 + so + rr) * QKV_N;
            sk[rr][dd] = sigma_f(rowp[2048 + h * 128 + dd]);
            sv[rr][dd] = rowp[3072 + h * 128 + dd];
        }
        __syncthreads();
        if (tid < 128) {
            #pragma unroll
            for (int rr = 0; rr < 8; ++rr) nacc += sk[rr][tid];
        }
        #pragma unroll
        for (int rr = 0; rr < 8; ++rr) {
            float4 k0 = *reinterpret_cast<float4*>(&sk[rr][tx * 8]);
            float4 k1 = *reinterpret_cast<float4*>(&sk[rr][tx * 8 + 4]);
            float4 v0 = *reinterpret_cast<float4*>(&sv[rr][ty * 8]);
            float4 v1 = *reinterpret_cast<float4*>(&sv[rr][ty * 8 + 4]);
            float kreg[8] = {k0.x,k0.y,k0.z,k0.w,k1.x,k1.y,k1.z,k1.w};
            float vreg[8] = {v0.x,v0.y,v0.z,v0.w,v1.x,v1.y,v1.z,v1.w};
            #pragma unroll
            for (int i = 0; i < 8; ++i)
                #pragma unroll
                for (int j2 = 0; j2 < 8; ++j2)
                    acc[i][j2] += kreg[i] * vreg[j2];
        }
        __syncthreads();
    }
    float* pb = part + ((size_t)sp * (BATCH * NKV) + b * NKV + h) * 16384;
    #pragma unroll
    for (int i = 0; i < 8; ++i)
        #pragma unroll
        for (int j2 = 0; j2 < 8; ++j2)
            pb[(tx * 8 + i) * 128 + ty * 8 + j2] = acc[i][j2];
    if (tid < 128)
        npart[((size_t)sp * (BATCH * NKV) + b * NKV + h) * 128 + tid] = nacc;
}

// K6: reduce partials + memory_in
__global__ void memred_k(const float* __restrict__ part, const float* __restrict__ mem_in,
                         float* __restrict__ out_mem)
{
    const size_t i = (size_t)blockIdx.x * 256 + threadIdx.x;   // 262144 total
    float a = mem_in[i];
    #pragma unroll
    for (int sp = 0; sp < NSPLIT; ++sp) a += part[(size_t)sp * 262144 + i];
    out_mem[i] = a;
}

// K6b: updated_norm = norm_in + sum_sp npart
__global__ void normred_k(const float* __restrict__ npart, const float* __restrict__ norm_in,
                          float* __restrict__ out_norm)
{
    const int bh = blockIdx.x, d = threadIdx.x;    // 16 blocks x 128 threads
    float a = norm_in[bh * 128 + d];
    #pragma unroll
    for (int sp = 0; sp < NSPLIT; ++sp)
        a += npart[((size_t)sp * (BATCH * NKV) + bh) * 128 + d];
    out_norm[bh * 128 + d] = a;
}

// =====================================================================
// K7: flash causal attention v3 — fixed-bound softmax, 2 waves x 32
// q-rows (2 m-tiles/wave: each Ks/Vs LDS fragment read feeds 2 MFMAs).
// Balanced q-tile pairs (x, 31-x); 128 threads.
// =====================================================================
__global__ __launch_bounds__(128) void attn_k(const __bf16* __restrict__ qr,
                                              const __bf16* __restrict__ kr,
                                              const __bf16* __restrict__ vt,
                                              const float* __restrict__ gate,
                                              const float* __restrict__ bnd,
                                              const float* __restrict__ maxp,
                                              __bf16* __restrict__ cb)
{
    __shared__ __align__(16) __bf16 Ks[64][136];     // 17.4 KB
    __shared__ __align__(16) __bf16 Vs[128][72];     // 18.4 KB
    __shared__ __align__(16) __bf16 plds[2][32][72]; //  9.2 KB

    const int tid = threadIdx.x, wave = tid >> 6, lane = tid & 63;
    const int l15 = lane & 15, l4 = lane >> 4;
    const int h = blockIdx.y, b = blockIdx.z;
    const int kvh = h >> 1;

    const __bf16* kbase = kr + (size_t)(b * NKV + kvh) * SEQ * 128;
    const __bf16* vbase = vt + (size_t)(b * NKV + kvh) * 128 * SEQ;
    const float* bbase  = bnd + (size_t)(b * NH + h) * SEQ;

    const float g  = 1.f / (1.f + __expf(-gate[h]));
    const float gi = 1.f - g;
    float kn2 = 0.f;
    const float* mp = maxp + (b * NKV + kvh) * 64;
    #pragma unroll
    for (int i = 0; i < 64; i += 4) {
        const float4 v = *reinterpret_cast<const float4*>(mp + i);
        kn2 = fmaxf(kn2, fmaxf(fmaxf(v.x, v.y), fmaxf(v.z, v.w)));
    }
    const float knmax = sqrtf(kn2);

    bf16x8 ones;
    #pragma unroll
    for (int j = 0; j < 8; ++j) ones[j] = (__bf16)1.0f;

    const int ks_r = tid >> 4, ks_c = (tid & 15) * 8;  // K: 8 rows/issue
    const int vs_r = tid >> 3, vs_c = (tid & 7) * 8;   // V: 16 rows/issue

    #pragma unroll 1
    for (int tile = 0; tile < 2; ++tile) {
        const int q0 = (tile == 0 ? blockIdx.x : 31 - blockIdx.x) * 64;
        const int qw = q0 + wave * 32;

        bf16x8 af[2][4];
        float m_r[2][4];
        #pragma unroll
        for (int m = 0; m < 2; ++m) {
            const __bf16* qb = qr + ((size_t)(b * NH + h) * SEQ + qw + m * 16 + l15) * 128;
            #pragma unroll
            for (int kb = 0; kb < 4; ++kb)
                af[m][kb] = *reinterpret_cast<const bf16x8*>(qb + kb * 32 + l4 * 8);
            #pragma unroll
            for (int r = 0; r < 4; ++r)
                m_r[m][r] = sqrtf(bbase[qw + m * 16 + l4 * 4 + r]) * knmax + 1.0f;
        }

        f32x4 o0[8] = {}, o1[8] = {};
        f32x4 lc0 = {}, lc1 = {};

        #pragma unroll 1
        for (int kt = 0; kt < q0 + 64; kt += 64) {
            // ---- cooperative staging of K (64x128) and V^T (128x64) ----
            #pragma unroll
            for (int rr = 0; rr < 8; ++rr)
                *reinterpret_cast<bf16x8*>(&Ks[rr * 8 + ks_r][ks_c]) =
                    *reinterpret_cast<const bf16x8*>(kbase + (size_t)(kt + rr * 8 + ks_r) * 128 + ks_c);
            #pragma unroll
            for (int rr = 0; rr < 8; ++rr)
                *reinterpret_cast<bf16x8*>(&Vs[rr * 16 + vs_r][vs_c]) =
                    *reinterpret_cast<const bf16x8*>(vbase + (size_t)(rr * 16 + vs_r) * SEQ + kt + vs_c);
            __syncthreads();

            // ---- QK^T for both m-tiles (Ks reads shared) ----
            f32x4 s0[4] = {}, s1[4] = {};
            #pragma unroll
            for (int kb = 0; kb < 4; ++kb) {
                #pragma unroll
                for (int sub = 0; sub < 4; ++sub) {
                    bf16x8 bb = *reinterpret_cast<bf16x8*>(&Ks[sub * 16 + l15][kb * 32 + l4 * 8]);
                    s0[sub] = mfma16(af[0][kb], bb, s0[sub]);
                    s1[sub] = mfma16(af[1][kb], bb, s1[sub]);
                }
            }

            // ---- exp with fixed bound + causal mask + store P ----
            #pragma unroll
            for (int r = 0; r < 4; ++r) {
                const int q0r = qw + l4 * 4 + r;
                const int q1r = q0r + 16;
                #pragma unroll
                for (int sub = 0; sub < 4; ++sub) {
                    const int key = kt + sub * 16 + l15;
                    float p0 = __expf(s0[sub][r] - m_r[0][r]);
                    float p1 = __expf(s1[sub][r] - m_r[1][r]);
                    p0 = (key <= q0r) ? p0 : 0.f;
                    p1 = (key <= q1r) ? p1 : 0.f;
                    plds[wave][l4 * 4 + r][sub * 16 + l15]      = (__bf16)p0;
                    plds[wave][16 + l4 * 4 + r][sub * 16 + l15] = (__bf16)p1;
                }
            }

            // ---- PV + row-sums (Vs reads shared across m-tiles) ----
            bf16x8 a00 = *reinterpret_cast<bf16x8*>(&plds[wave][l15][l4 * 8]);
            bf16x8 a01 = *reinterpret_cast<bf16x8*>(&plds[wave][l15][32 + l4 * 8]);
            bf16x8 a10 = *reinterpret_cast<bf16x8*>(&plds[wave][16 + l15][l4 * 8]);
            bf16x8 a11 = *reinterpret_cast<bf16x8*>(&plds[wave][16 + l15][32 + l4 * 8]);
            lc0 = mfma16(a00, ones, lc0); lc0 = mfma16(a01, ones, lc0);
            lc1 = mfma16(a10, ones, lc1); lc1 = mfma16(a11, ones, lc1);
            #pragma unroll
            for (int nc = 0; nc < 8; ++nc) {
                bf16x8 b0 = *reinterpret_cast<bf16x8*>(&Vs[nc * 16 + l15][l4 * 8]);
                bf16x8 b1 = *reinterpret_cast<bf16x8*>(&Vs[nc * 16 + l15][32 + l4 * 8]);
                o0[nc] = mfma16(a00, b0, o0[nc]); o0[nc] = mfma16(a01, b1, o0[nc]);
                o1[nc] = mfma16(a10, b0, o1[nc]); o1[nc] = mfma16(a11, b1, o1[nc]);
            }
            __syncthreads();
        }

        // ---- epilogue: add (1-g) * attn / li into combined ----
        #pragma unroll
        for (int r = 0; r < 4; ++r) {
            const int qrow = qw + l4 * 4 + r;
            const float i0 = gi / lc0[r];
            const float i1 = gi / lc1[r];
            __bf16* c0 = cb + (size_t)(b * SEQ + qrow) * HID + h * 128;
            __bf16* c1 = cb + (size_t)(b * SEQ + qrow + 16) * HID + h * 128;
            #pragma unroll
            for (int nc = 0; nc < 8; ++nc) {
                const int dd = nc * 16 + l15;
                c0[dd] = (__bf16)((float)c0[dd] + o0[nc][r] * i0);
                c1[dd] = (__bf16)((float)c1[dd] + o1[nc][r] * i1);
            }
        }
    }
}

// =====================================================================
extern "C" void kernel_launch(void* const* d_in, const int* in_sizes, int n_in,
                              void* d_out, int out_size, void* d_ws, size_t ws_size,
                              hipStream_t stream)
{
    const float* hidden  = (const float*)d_in[0];
    const float* Wq      = (const float*)d_in[1];
    const float* Wk      = (const float*)d_in[2];
    const float* Wv      = (const float*)d_in[3];
    const float* Wo      = (const float*)d_in[4];
    const float* gate    = (const float*)d_in[5];
    const float* mem_in  = (const float*)d_in[6];
    const float* norm_in = (const float*)d_in[7];
    const int*   pos     = (const int*)d_in[8];

    float* out_final = (float*)d_out;                  // (B,S,HID)
    float* out_mem   = out_final + (size_t)BATCH * SEQ * HID;     // (B,8,128,128)
    float* out_norm  = out_mem + (size_t)BATCH * NKV * 128 * 128; // (B,8,1,128)

    char* ws = (char*)d_ws;
    float*  qkv  = (float*)(ws + OFF_QKV);
    __bf16* sq   = (__bf16*)(ws + OFF_SQ);
    __bf16* qrb  = (__bf16*)(ws + OFF_QR);
    __bf16* krb  = (__bf16*)(ws + OFF_KR);
    __bf16* vtb  = (__bf16*)(ws + OFF_VT);
    float*  nd   = (float*)(ws + OFF_ND);
    __bf16* cb   = (__bf16*)(ws + OFF_CB);
    float*  part = (float*)(ws + OFF_PART);
    float*  bnd  = (float*)(ws + OFF_BND);
    float*  maxp = (float*)(ws + OFF_MAXP);
    float*  npart = (float*)(ws + OFF_NPART);
    // overlays (lifetimes disjoint from the named owners):
    __bf16* hb   = (__bf16*)(ws + OFF_SQ);    // bf16 hidden  [4096][2048], dead after gemm1
    __bf16* qkvT = (__bf16*)(ws + OFF_QR);    // bf16 W_qkv^T [4096][2048], dead after gemm1
    __bf16* woT  = (__bf16*)(ws + OFF_PART);  // bf16 Wo^T    [2048][2048], after memred

    // 0. bf16 conversions / weight transposes
    f2b_k<<<(M_ROWS * HID) / (256 * 8), 256, 0, stream>>>(hidden, hb);
    tr_k<<<dim3(HID / 64, 2048 / 64), 256, 0, stream>>>(Wq, qkvT, HID, 2048);
    tr_k<<<dim3(HID / 64, 1024 / 64), 256, 0, stream>>>(Wk, qkvT + (size_t)2048 * HID, HID, 1024);
    tr_k<<<dim3(HID / 64, 1024 / 64), 256, 0, stream>>>(Wv, qkvT + (size_t)3072 * HID, HID, 1024);

    // 1. fused QKV projection: [4096 x 2048] @ [2048 x 4096]
    gemm_bt<<<dim3(M_ROWS / 128, QKV_N / 128), 256, 0, stream>>>(hb, qkvT, qkv, QKV_N, HID);

    // 2. prep (overwrites hb/qkvT — now dead); k-norm maxima fused in
    prep_k<<<dim3(SEQ / 32, NKV, BATCH), 256, 0, stream>>>(qkv, norm_in, pos, sq, qrb, krb, vtb,
                                                           nd, bnd, maxp);

    // 3. memory_output -> combined (g * memout / nd)
    memout_k<<<dim3(SEQ / 64, NH, BATCH), 256, 0, stream>>>(sq, mem_in, nd, gate, cb);

    // 4/5. updated_memory (+ sigma_k col-sum partials)
    memupd_k<<<dim3(NSPLIT, NKV, BATCH), 256, 0, stream>>>(qkv, part, npart);
    memred_k<<<(BATCH * NKV * 128 * 128) / 256, 256, 0, stream>>>(part, mem_in, out_mem);
    normred_k<<<BATCH * NKV, 128, 0, stream>>>(npart, norm_in, out_norm);

    // 6b. Wo^T (overlays part — dead after memred)
    tr_k<<<dim3(HID / 64, HID / 64), 256, 0, stream>>>(Wo, woT, HID, HID);

    // 7. causal attention (fixed-bound softmax, 2x32 rows/wave)
    attn_k<<<dim3(16, NH, BATCH), 128, 0, stream>>>(qrb, krb, vtb, gate, bnd, maxp, cb);

    // 8. output projection: [4096 x 2048] @ [2048 x 2048]
    gemm_bt<<<dim3(M_ROWS / 128, HID / 128), 256, 0, stream>>>(cb, woT, out_final, HID, HID);
}